// Round 1
// baseline (1160.713 us; speedup 1.0000x reference)
//
#include <hip/hip_runtime.h>

#define N_NODES 50000
#define N_EDGES 600000
// feature dims: IN=128, HID=64, OUT=128

// ---------------- workspace layout (float offsets) ----------------
#define WS_XS   0                    // N*128 = 6,400,000
#define WS_ES   6400000              // 6,400,000
#define WS_DEG  12800000             // 50,000 (float counts)
#define WS_ZERO_FLOATS 12850000      // memset range [0, here)
#define WS_U    12850000             // 64*128 = 8192
#define WS_V    12858192             // 128*128 = 16384
#define WS_G    12874576             // 8192
#define WS_P    12882768             // 16384
#define WS_Q    12899152             // 16384
#define WS_C1   12915536             // 16384
#define WS_BE   12931920             // 128
#define WS_R    12932048             // 128
#define WS_C2   12932176             // 128

// ---------------- small fused-matrix precompute ----------------
// pre1: U = W1@W2, V = W_ml@W_em, C1 = W_nl2@W_em, be = b1@W2+b2,
//       c2 = (b_nl2+b_ml)@W_em + b_em     (inputs only)
__global__ void pre1_kernel(const float* __restrict__ W1, const float* __restrict__ W2,
                            const float* __restrict__ b1, const float* __restrict__ b2,
                            const float* __restrict__ W_ml, const float* __restrict__ W_em,
                            const float* __restrict__ W_nl2, const float* __restrict__ b_nl2,
                            const float* __restrict__ b_ml, const float* __restrict__ b_em,
                            float* __restrict__ U, float* __restrict__ V,
                            float* __restrict__ C1, float* __restrict__ be,
                            float* __restrict__ c2) {
    int idx = blockIdx.x * 256 + threadIdx.x;
    if (idx < 8192) {                       // U[64][128]
        int i = idx >> 7, j = idx & 127;
        float s = 0.f;
        for (int k = 0; k < 64; ++k) s += W1[i*64+k] * W2[k*128+j];
        U[idx] = s;
    } else if (idx < 24576) {               // V[128][128]
        int t = idx - 8192; int i = t >> 7, j = t & 127;
        float s = 0.f;
        for (int k = 0; k < 64; ++k) s += W_ml[i*64+k] * W_em[k*128+j];
        V[t] = s;
    } else if (idx < 40960) {               // C1[128][128]
        int t = idx - 24576; int i = t >> 7, j = t & 127;
        float s = 0.f;
        for (int k = 0; k < 64; ++k) s += W_nl2[i*64+k] * W_em[k*128+j];
        C1[t] = s;
    } else if (idx < 41088) {               // be[128]
        int j = idx - 40960;
        float s = b2[j];
        for (int k = 0; k < 64; ++k) s += b1[k] * W2[k*128+j];
        be[j] = s;
    } else if (idx < 41216) {               // c2[128]
        int j = idx - 41088;
        float s = b_em[j];
        for (int k = 0; k < 64; ++k) s += (b_nl2[k] + b_ml[k]) * W_em[k*128+j];
        c2[j] = s;
    }
}

// pre2: G = U @ V   [64][128], K=128
__global__ void pre2_kernel(const float* __restrict__ U, const float* __restrict__ V,
                            float* __restrict__ G) {
    int idx = blockIdx.x * 256 + threadIdx.x;
    if (idx >= 8192) return;
    int i = idx >> 7, j = idx & 127;
    float s = 0.f;
    for (int k = 0; k < 128; ++k) s += U[i*128+k] * V[k*128+j];
    G[idx] = s;
}

// pre3: P = W_nl1@G, Q = W_el@G, r = (b_nl1+b_el)@G + be@V
__global__ void pre3_kernel(const float* __restrict__ W_nl1, const float* __restrict__ W_el,
                            const float* __restrict__ b_nl1, const float* __restrict__ b_el,
                            const float* __restrict__ G, const float* __restrict__ V,
                            const float* __restrict__ be,
                            float* __restrict__ P, float* __restrict__ Q,
                            float* __restrict__ r) {
    int idx = blockIdx.x * 256 + threadIdx.x;
    if (idx < 16384) {
        int i = idx >> 7, j = idx & 127;
        float s = 0.f;
        for (int k = 0; k < 64; ++k) s += W_nl1[i*64+k] * G[k*128+j];
        P[idx] = s;
    } else if (idx < 32768) {
        int t = idx - 16384; int i = t >> 7, j = t & 127;
        float s = 0.f;
        for (int k = 0; k < 64; ++k) s += W_el[i*64+k] * G[k*128+j];
        Q[t] = s;
    } else if (idx < 32896) {
        int j = idx - 32768;
        float s = 0.f;
        for (int k = 0; k < 64; ++k)  s += (b_nl1[k] + b_el[k]) * G[k*128+j];
        for (int k = 0; k < 128; ++k) s += be[k] * V[k*128+j];
        r[j] = s;
    }
}

// ---------------- edge scatter: xs[dst] += x[src], es[dst] += e, deg[dst] += 1 ----------------
// One wave (64 lanes) per edge; each lane handles a float2 (whole 512B row per wave).
__global__ __launch_bounds__(256) void scatter_kernel(
        const float* __restrict__ x, const float* __restrict__ ef,
        const int* __restrict__ src, const int* __restrict__ dst,
        float* __restrict__ xs, float* __restrict__ es, float* __restrict__ deg) {
    int edge = (int)((blockIdx.x * 256 + threadIdx.x) >> 6);
    int lane = threadIdx.x & 63;
    if (edge >= N_EDGES) return;
    int s = src[edge], d = dst[edge];
    float2 xv = *(const float2*)(x  + (size_t)s * 128 + lane * 2);
    float2 ev = *(const float2*)(ef + (size_t)edge * 128 + lane * 2);
    float* xd = xs + (size_t)d * 128 + lane * 2;
    float* ed = es + (size_t)d * 128 + lane * 2;
    atomicAdd(xd,     xv.x);
    atomicAdd(xd + 1, xv.y);
    atomicAdd(ed,     ev.x);
    atomicAdd(ed + 1, ev.y);
    if (lane == 0) atomicAdd(deg + d, 1.0f);
}

// ---------------- final fused GEMM: out = x@C1 + xs@P + es@Q + deg*r + c2 ----------------
// Block: 256 threads, 32 node-rows. A-panel [32][384] in LDS (x|xs|es).
// Thread: 2 cols (c, c+64) x 8 rows -> 16 outputs. Broadcast ds_read_b128 on A.
__global__ __launch_bounds__(256) void out_gemm_kernel(
        const float* __restrict__ x, const float* __restrict__ xs, const float* __restrict__ es,
        const float* __restrict__ deg,
        const float* __restrict__ C1, const float* __restrict__ P, const float* __restrict__ Q,
        const float* __restrict__ rvec, const float* __restrict__ c2,
        float* __restrict__ out) {
    __shared__ float A[32][384];   // 48 KB
    int base = blockIdx.x * 32;

    for (int idx = threadIdx.x; idx < 32 * 96; idx += 256) {
        int row = idx / 96, c4 = idx - row * 96;
        int n = base + row;
        float4 v = make_float4(0.f, 0.f, 0.f, 0.f);
        if (n < N_NODES) {
            const float* p = (c4 < 32) ? (x  + (size_t)n * 128 + c4 * 4)
                           : (c4 < 64) ? (xs + (size_t)n * 128 + (c4 - 32) * 4)
                                       : (es + (size_t)n * 128 + (c4 - 64) * 4);
            v = *(const float4*)p;
        }
        *(float4*)&A[row][c4 * 4] = v;
    }
    __syncthreads();

    int c    = threadIdx.x & 63;
    int rg   = threadIdx.x >> 6;     // wave id 0..3 (uniform per wave)
    int rowb = rg * 8;

    float rc0 = rvec[c], rc1 = rvec[c + 64];
    float bc0 = c2[c],   bc1 = c2[c + 64];
    float acc0[8], acc1[8];
    #pragma unroll
    for (int q = 0; q < 8; ++q) {
        int n = base + rowb + q;
        float dg = (n < N_NODES) ? deg[n] : 0.f;
        acc0[q] = bc0 + dg * rc0;
        acc1[q] = bc1 + dg * rc1;
    }

    const float* Ws[3] = {C1, P, Q};
    #pragma unroll
    for (int m = 0; m < 3; ++m) {
        const float* __restrict__ W = Ws[m];
        const int kb = m * 128;
        for (int k = 0; k < 128; k += 4) {
            float w00 = W[(k+0)*128 + c],      w10 = W[(k+1)*128 + c],
                  w20 = W[(k+2)*128 + c],      w30 = W[(k+3)*128 + c];
            float w01 = W[(k+0)*128 + c + 64], w11 = W[(k+1)*128 + c + 64],
                  w21 = W[(k+2)*128 + c + 64], w31 = W[(k+3)*128 + c + 64];
            #pragma unroll
            for (int q = 0; q < 8; ++q) {
                const float4 a = *(const float4*)&A[rowb + q][kb + k];
                acc0[q] += a.x * w00 + a.y * w10 + a.z * w20 + a.w * w30;
                acc1[q] += a.x * w01 + a.y * w11 + a.z * w21 + a.w * w31;
            }
        }
    }

    #pragma unroll
    for (int q = 0; q < 8; ++q) {
        int n = base + rowb + q;
        if (n < N_NODES) {
            out[(size_t)n * 128 + c]      = acc0[q];
            out[(size_t)n * 128 + c + 64] = acc1[q];
        }
    }
}

extern "C" void kernel_launch(void* const* d_in, const int* in_sizes, int n_in,
                              void* d_out, int out_size, void* d_ws, size_t ws_size,
                              hipStream_t stream) {
    const float* x     = (const float*)d_in[0];
    const float* ef    = (const float*)d_in[1];
    const int*   src   = (const int*)d_in[2];
    const int*   dst   = (const int*)d_in[3];
    const float* W_nl1 = (const float*)d_in[4];
    const float* b_nl1 = (const float*)d_in[5];
    const float* W_el  = (const float*)d_in[6];
    const float* b_el  = (const float*)d_in[7];
    const float* W1    = (const float*)d_in[8];
    const float* b1    = (const float*)d_in[9];
    const float* W2    = (const float*)d_in[10];
    const float* b2    = (const float*)d_in[11];
    const float* W_nl2 = (const float*)d_in[12];
    const float* b_nl2 = (const float*)d_in[13];
    const float* W_ml  = (const float*)d_in[14];
    const float* b_ml  = (const float*)d_in[15];
    const float* W_em  = (const float*)d_in[16];
    const float* b_em  = (const float*)d_in[17];

    float* ws  = (float*)d_ws;
    float* xs  = ws + WS_XS;
    float* es  = ws + WS_ES;
    float* deg = ws + WS_DEG;
    float* U   = ws + WS_U;
    float* V   = ws + WS_V;
    float* G   = ws + WS_G;
    float* P   = ws + WS_P;
    float* Q   = ws + WS_Q;
    float* C1  = ws + WS_C1;
    float* be  = ws + WS_BE;
    float* r   = ws + WS_R;
    float* c2  = ws + WS_C2;

    // zero the accumulators (xs, es, deg)
    hipMemsetAsync(ws, 0, (size_t)WS_ZERO_FLOATS * sizeof(float), stream);

    pre1_kernel<<<(41216 + 255) / 256, 256, 0, stream>>>(
        W1, W2, b1, b2, W_ml, W_em, W_nl2, b_nl2, b_ml, b_em, U, V, C1, be, c2);
    pre2_kernel<<<8192 / 256, 256, 0, stream>>>(U, V, G);
    pre3_kernel<<<(32896 + 255) / 256, 256, 0, stream>>>(
        W_nl1, W_el, b_nl1, b_el, G, V, be, P, Q, r);

    scatter_kernel<<<N_EDGES / 4, 256, 0, stream>>>(x, ef, src, dst, xs, es, deg);

    out_gemm_kernel<<<(N_NODES + 31) / 32, 256, 0, stream>>>(
        x, xs, es, deg, C1, P, Q, r, c2, (float*)d_out);
}

// Round 2
// 399.941 us; speedup vs baseline: 2.9022x; 2.9022x over previous
//
#include <hip/hip_runtime.h>

#define N_NODES 50000
#define N_EDGES 600000
// feature dims: IN=128, HID=64, OUT=128

// ---------------- workspace layout ----------------
// int region (element offsets into (int*)d_ws)
#define WI_CNT   0          // 50000
#define WI_OFF   50000      // 50000  (exclusive scan of cnt)
#define WI_CUR   100000     // 50000  (fill cursors)
#define WI_BSUM  150000     // 256
#define WI_BOFF  150256     // 256
#define WI_EIDS  150512     // 600000 -> ends 750512
// float region (element offsets into (float*)d_ws)
#define WF_U    760000      // 64*128  = 8192
#define WF_V    768192      // 128*128 = 16384
#define WF_G    784576      // 8192
#define WF_P    792768      // 16384
#define WF_Q    809152      // 16384
#define WF_C1   825536      // 16384
#define WF_BE   841920      // 128
#define WF_R    842048      // 128
#define WF_C2   842176      // 128

#define NBLK_SCAN 196       // ceil(50000/256)

// ---------------- small fused-matrix precompute ----------------
__global__ void pre1_kernel(const float* __restrict__ W1, const float* __restrict__ W2,
                            const float* __restrict__ b1, const float* __restrict__ b2,
                            const float* __restrict__ W_ml, const float* __restrict__ W_em,
                            const float* __restrict__ W_nl2, const float* __restrict__ b_nl2,
                            const float* __restrict__ b_ml, const float* __restrict__ b_em,
                            float* __restrict__ U, float* __restrict__ V,
                            float* __restrict__ C1, float* __restrict__ be,
                            float* __restrict__ c2) {
    int idx = blockIdx.x * 256 + threadIdx.x;
    if (idx < 8192) {                       // U[64][128] = W1@W2
        int i = idx >> 7, j = idx & 127;
        float s = 0.f;
        for (int k = 0; k < 64; ++k) s += W1[i*64+k] * W2[k*128+j];
        U[idx] = s;
    } else if (idx < 24576) {               // V[128][128] = W_ml@W_em
        int t = idx - 8192; int i = t >> 7, j = t & 127;
        float s = 0.f;
        for (int k = 0; k < 64; ++k) s += W_ml[i*64+k] * W_em[k*128+j];
        V[t] = s;
    } else if (idx < 40960) {               // C1[128][128] = W_nl2@W_em
        int t = idx - 24576; int i = t >> 7, j = t & 127;
        float s = 0.f;
        for (int k = 0; k < 64; ++k) s += W_nl2[i*64+k] * W_em[k*128+j];
        C1[t] = s;
    } else if (idx < 41088) {               // be[128] = b1@W2 + b2
        int j = idx - 40960;
        float s = b2[j];
        for (int k = 0; k < 64; ++k) s += b1[k] * W2[k*128+j];
        be[j] = s;
    } else if (idx < 41216) {               // c2[128] = (b_nl2+b_ml)@W_em + b_em
        int j = idx - 41088;
        float s = b_em[j];
        for (int k = 0; k < 64; ++k) s += (b_nl2[k] + b_ml[k]) * W_em[k*128+j];
        c2[j] = s;
    }
}

__global__ void pre2_kernel(const float* __restrict__ U, const float* __restrict__ V,
                            float* __restrict__ G) {
    int idx = blockIdx.x * 256 + threadIdx.x;
    if (idx >= 8192) return;
    int i = idx >> 7, j = idx & 127;
    float s = 0.f;
    for (int k = 0; k < 128; ++k) s += U[i*128+k] * V[k*128+j];
    G[idx] = s;
}

__global__ void pre3_kernel(const float* __restrict__ W_nl1, const float* __restrict__ W_el,
                            const float* __restrict__ b_nl1, const float* __restrict__ b_el,
                            const float* __restrict__ G, const float* __restrict__ V,
                            const float* __restrict__ be,
                            float* __restrict__ P, float* __restrict__ Q,
                            float* __restrict__ r) {
    int idx = blockIdx.x * 256 + threadIdx.x;
    if (idx < 16384) {                      // P = W_nl1@G
        int i = idx >> 7, j = idx & 127;
        float s = 0.f;
        for (int k = 0; k < 64; ++k) s += W_nl1[i*64+k] * G[k*128+j];
        P[idx] = s;
    } else if (idx < 32768) {               // Q = W_el@G
        int t = idx - 16384; int i = t >> 7, j = t & 127;
        float s = 0.f;
        for (int k = 0; k < 64; ++k) s += W_el[i*64+k] * G[k*128+j];
        Q[t] = s;
    } else if (idx < 32896) {               // r = (b_nl1+b_el)@G + be@V
        int j = idx - 32768;
        float s = 0.f;
        for (int k = 0; k < 64; ++k)  s += (b_nl1[k] + b_el[k]) * G[k*128+j];
        for (int k = 0; k < 128; ++k) s += be[k] * V[k*128+j];
        r[j] = s;
    }
}

// ---------------- CSR build: histogram, scan, bucket fill ----------------
__global__ __launch_bounds__(256) void hist_kernel(const int* __restrict__ dst,
                                                   int* __restrict__ cnt) {
    int e = blockIdx.x * 256 + threadIdx.x;
    if (e < N_EDGES) atomicAdd(&cnt[dst[e]], 1);
}

// per-256-chunk sums
__global__ __launch_bounds__(256) void scan_a_kernel(const int* __restrict__ cnt,
                                                     int* __restrict__ bsum) {
    __shared__ int s[256];
    int i = blockIdx.x * 256 + threadIdx.x;
    int v = (i < N_NODES) ? cnt[i] : 0;
    s[threadIdx.x] = v;
    __syncthreads();
    for (int d = 128; d > 0; d >>= 1) {
        if (threadIdx.x < d) s[threadIdx.x] += s[threadIdx.x + d];
        __syncthreads();
    }
    if (threadIdx.x == 0) bsum[blockIdx.x] = s[0];
}

// exclusive scan of the block sums (single block)
__global__ __launch_bounds__(256) void scan_b_kernel(const int* __restrict__ bsum,
                                                     int* __restrict__ boff) {
    __shared__ int s[256];
    int t = threadIdx.x;
    int v = (t < NBLK_SCAN) ? bsum[t] : 0;
    s[t] = v;
    __syncthreads();
    for (int d = 1; d < 256; d <<= 1) {
        int tv = (t >= d) ? s[t - d] : 0;
        __syncthreads();
        s[t] += tv;
        __syncthreads();
    }
    if (t < NBLK_SCAN) boff[t] = s[t] - v;   // exclusive
}

// exclusive scan within chunk + chunk offset -> offsets, cursor
__global__ __launch_bounds__(256) void scan_c_kernel(const int* __restrict__ cnt,
                                                     const int* __restrict__ boff,
                                                     int* __restrict__ offs,
                                                     int* __restrict__ cursor) {
    __shared__ int s[256];
    int i = blockIdx.x * 256 + threadIdx.x;
    int t = threadIdx.x;
    int v = (i < N_NODES) ? cnt[i] : 0;
    s[t] = v;
    __syncthreads();
    for (int d = 1; d < 256; d <<= 1) {
        int tv = (t >= d) ? s[t - d] : 0;
        __syncthreads();
        s[t] += tv;
        __syncthreads();
    }
    if (i < N_NODES) {
        int ex = s[t] - v + boff[blockIdx.x];
        offs[i] = ex;
        cursor[i] = ex;
    }
}

__global__ __launch_bounds__(256) void fill_kernel(const int* __restrict__ dst,
                                                   int* __restrict__ cursor,
                                                   int* __restrict__ eids) {
    int e = blockIdx.x * 256 + threadIdx.x;
    if (e < N_EDGES) {
        int pos = atomicAdd(&cursor[dst[e]], 1);
        eids[pos] = e;
    }
}

// ---------------- fused gather + output GEMM ----------------
// out = x@C1 + xs@P + es@Q + deg*r + c2, where xs/es are gathered in-block.
// Block: 256 threads = 4 waves, 32 node-rows (8 per wave). A-panel [32][384] LDS.
__global__ __launch_bounds__(256) void fused_gather_gemm(
        const float* __restrict__ x, const float* __restrict__ ef,
        const int* __restrict__ src,
        const int* __restrict__ cnt, const int* __restrict__ offs,
        const int* __restrict__ eids,
        const float* __restrict__ C1, const float* __restrict__ P,
        const float* __restrict__ Q,
        const float* __restrict__ rvec, const float* __restrict__ c2,
        float* __restrict__ out) {
    __shared__ float A[32][384];   // 48 KB: [x | xs | es]
    int base = blockIdx.x * 32;
    int tid  = threadIdx.x;
    int lane = tid & 63;
    int wave = tid >> 6;

    // phase 1: x rows -> A[:][0:128]
    for (int idx = tid; idx < 32 * 32; idx += 256) {
        int row = idx >> 5, c4 = idx & 31;
        int n = base + row;
        float4 v = make_float4(0.f, 0.f, 0.f, 0.f);
        if (n < N_NODES) v = *(const float4*)(x + (size_t)n * 128 + c4 * 4);
        *(float4*)&A[row][c4 * 4] = v;
    }

    // phase 2: gather xs/es rows; wave w owns rows [8w, 8w+8)
    for (int q = 0; q < 8; ++q) {
        int row = wave * 8 + q;
        int n = base + row;
        float2 ax = make_float2(0.f, 0.f), ae = make_float2(0.f, 0.f);
        if (n < N_NODES) {
            int off = offs[n], deg = cnt[n];
            for (int c0 = 0; c0 < deg; c0 += 64) {
                int myeid = 0, mysrc = 0;
                int j = c0 + lane;
                if (j < deg) { myeid = eids[off + j]; mysrc = src[myeid]; }
                int m = deg - c0; if (m > 64) m = 64;
                for (int j2 = 0; j2 < m; ++j2) {
                    int eid = __shfl(myeid, j2);
                    int s   = __shfl(mysrc, j2);
                    float2 xv = *(const float2*)(x  + (size_t)s   * 128 + lane * 2);
                    float2 ev = *(const float2*)(ef + (size_t)eid * 128 + lane * 2);
                    ax.x += xv.x; ax.y += xv.y;
                    ae.x += ev.x; ae.y += ev.y;
                }
            }
        }
        *(float2*)&A[row][128 + lane * 2] = ax;
        *(float2*)&A[row][256 + lane * 2] = ae;
    }
    __syncthreads();

    // phase 3: GEMM. Thread: cols (c, c+64) x 8 rows of its wave.
    int c    = lane;
    int rowb = wave * 8;

    float rc0 = rvec[c], rc1 = rvec[c + 64];
    float bc0 = c2[c],   bc1 = c2[c + 64];
    float acc0[8], acc1[8];
    #pragma unroll
    for (int q = 0; q < 8; ++q) {
        int n = base + rowb + q;
        float dg = (n < N_NODES) ? (float)cnt[n] : 0.f;
        acc0[q] = bc0 + dg * rc0;
        acc1[q] = bc1 + dg * rc1;
    }

    const float* Ws[3] = {C1, P, Q};
    #pragma unroll
    for (int m = 0; m < 3; ++m) {
        const float* __restrict__ W = Ws[m];
        const int kb = m * 128;
        for (int k = 0; k < 128; k += 4) {
            float w00 = W[(k+0)*128 + c],      w10 = W[(k+1)*128 + c],
                  w20 = W[(k+2)*128 + c],      w30 = W[(k+3)*128 + c];
            float w01 = W[(k+0)*128 + c + 64], w11 = W[(k+1)*128 + c + 64],
                  w21 = W[(k+2)*128 + c + 64], w31 = W[(k+3)*128 + c + 64];
            #pragma unroll
            for (int q = 0; q < 8; ++q) {
                const float4 a = *(const float4*)&A[rowb + q][kb + k];
                acc0[q] += a.x * w00 + a.y * w10 + a.z * w20 + a.w * w30;
                acc1[q] += a.x * w01 + a.y * w11 + a.z * w21 + a.w * w31;
            }
        }
    }

    #pragma unroll
    for (int q = 0; q < 8; ++q) {
        int n = base + rowb + q;
        if (n < N_NODES) {
            out[(size_t)n * 128 + c]      = acc0[q];
            out[(size_t)n * 128 + c + 64] = acc1[q];
        }
    }
}

extern "C" void kernel_launch(void* const* d_in, const int* in_sizes, int n_in,
                              void* d_out, int out_size, void* d_ws, size_t ws_size,
                              hipStream_t stream) {
    const float* x     = (const float*)d_in[0];
    const float* ef    = (const float*)d_in[1];
    const int*   src   = (const int*)d_in[2];
    const int*   dst   = (const int*)d_in[3];
    const float* W_nl1 = (const float*)d_in[4];
    const float* b_nl1 = (const float*)d_in[5];
    const float* W_el  = (const float*)d_in[6];
    const float* b_el  = (const float*)d_in[7];
    const float* W1    = (const float*)d_in[8];
    const float* b1    = (const float*)d_in[9];
    const float* W2    = (const float*)d_in[10];
    const float* b2    = (const float*)d_in[11];
    const float* W_nl2 = (const float*)d_in[12];
    const float* b_nl2 = (const float*)d_in[13];
    const float* W_ml  = (const float*)d_in[14];
    const float* b_ml  = (const float*)d_in[15];
    const float* W_em  = (const float*)d_in[16];
    const float* b_em  = (const float*)d_in[17];

    int*   wsI = (int*)d_ws;
    float* wsF = (float*)d_ws;
    int* cnt    = wsI + WI_CNT;
    int* offs   = wsI + WI_OFF;
    int* cursor = wsI + WI_CUR;
    int* bsum   = wsI + WI_BSUM;
    int* boff   = wsI + WI_BOFF;
    int* eids   = wsI + WI_EIDS;
    float* U  = wsF + WF_U;
    float* V  = wsF + WF_V;
    float* G  = wsF + WF_G;
    float* P  = wsF + WF_P;
    float* Q  = wsF + WF_Q;
    float* C1 = wsF + WF_C1;
    float* be = wsF + WF_BE;
    float* r  = wsF + WF_R;
    float* c2 = wsF + WF_C2;

    // zero histogram
    hipMemsetAsync(cnt, 0, N_NODES * sizeof(int), stream);

    // fused-weight precompute (tiny)
    pre1_kernel<<<(41216 + 255) / 256, 256, 0, stream>>>(
        W1, W2, b1, b2, W_ml, W_em, W_nl2, b_nl2, b_ml, b_em, U, V, C1, be, c2);
    pre2_kernel<<<8192 / 256, 256, 0, stream>>>(U, V, G);
    pre3_kernel<<<(32896 + 255) / 256, 256, 0, stream>>>(
        W_nl1, W_el, b_nl1, b_el, G, V, be, P, Q, r);

    // CSR build
    hist_kernel<<<(N_EDGES + 255) / 256, 256, 0, stream>>>(dst, cnt);
    scan_a_kernel<<<NBLK_SCAN, 256, 0, stream>>>(cnt, bsum);
    scan_b_kernel<<<1, 256, 0, stream>>>(bsum, boff);
    scan_c_kernel<<<NBLK_SCAN, 256, 0, stream>>>(cnt, boff, offs, cursor);
    fill_kernel<<<(N_EDGES + 255) / 256, 256, 0, stream>>>(dst, cursor, eids);

    // fused gather + GEMM
    fused_gather_gemm<<<(N_NODES + 31) / 32, 256, 0, stream>>>(
        x, ef, src, cnt, offs, eids, C1, P, Q, r, c2, (float*)d_out);
}

// Round 3
// 329.823 us; speedup vs baseline: 3.5192x; 1.2126x over previous
//
#include <hip/hip_runtime.h>

#define N_NODES 50000
#define N_EDGES 600000
// feature dims: IN=128, HID=64, OUT=128

// ---------------- workspace layout ----------------
// floats first: xs, es
#define WF_XS   0            // 6,400,000 floats
#define WF_ES   6400000      // 6,400,000 floats
// ints (element offsets into (int*)d_ws)
#define WI_CNT   12800000    // 50000
#define WI_OFF   12850000    // 50000
#define WI_CUR   12900000    // 50000
#define WI_BSUM  12950000    // 256
#define WI_BOFF  12950256    // 256
#define WI_EIDS  12950512    // 600000 -> ends 13550512
// small float region
#define WF_U    13560000     // 64*128  = 8192
#define WF_V    13568192     // 128*128 = 16384
#define WF_G    13584576     // 8192
#define WF_P    13592768     // 16384
#define WF_Q    13609152     // 16384
#define WF_C1   13625536     // 16384
#define WF_BE   13641920     // 128
#define WF_R    13642048     // 128
#define WF_C2   13642176     // 128
// total ~13.65M elems * 4B = 54.6 MB

#define NBLK_SCAN 196        // ceil(50000/256)

// ---------------- small fused-matrix precompute ----------------
__global__ void pre1_kernel(const float* __restrict__ W1, const float* __restrict__ W2,
                            const float* __restrict__ b1, const float* __restrict__ b2,
                            const float* __restrict__ W_ml, const float* __restrict__ W_em,
                            const float* __restrict__ W_nl2, const float* __restrict__ b_nl2,
                            const float* __restrict__ b_ml, const float* __restrict__ b_em,
                            float* __restrict__ U, float* __restrict__ V,
                            float* __restrict__ C1, float* __restrict__ be,
                            float* __restrict__ c2) {
    int idx = blockIdx.x * 256 + threadIdx.x;
    if (idx < 8192) {                       // U[64][128] = W1@W2
        int i = idx >> 7, j = idx & 127;
        float s = 0.f;
        for (int k = 0; k < 64; ++k) s += W1[i*64+k] * W2[k*128+j];
        U[idx] = s;
    } else if (idx < 24576) {               // V[128][128] = W_ml@W_em
        int t = idx - 8192; int i = t >> 7, j = t & 127;
        float s = 0.f;
        for (int k = 0; k < 64; ++k) s += W_ml[i*64+k] * W_em[k*128+j];
        V[t] = s;
    } else if (idx < 40960) {               // C1[128][128] = W_nl2@W_em
        int t = idx - 24576; int i = t >> 7, j = t & 127;
        float s = 0.f;
        for (int k = 0; k < 64; ++k) s += W_nl2[i*64+k] * W_em[k*128+j];
        C1[t] = s;
    } else if (idx < 41088) {               // be[128] = b1@W2 + b2
        int j = idx - 40960;
        float s = b2[j];
        for (int k = 0; k < 64; ++k) s += b1[k] * W2[k*128+j];
        be[j] = s;
    } else if (idx < 41216) {               // c2[128] = (b_nl2+b_ml)@W_em + b_em
        int j = idx - 41088;
        float s = b_em[j];
        for (int k = 0; k < 64; ++k) s += (b_nl2[k] + b_ml[k]) * W_em[k*128+j];
        c2[j] = s;
    }
}

__global__ void pre2_kernel(const float* __restrict__ U, const float* __restrict__ V,
                            float* __restrict__ G) {
    int idx = blockIdx.x * 256 + threadIdx.x;
    if (idx >= 8192) return;
    int i = idx >> 7, j = idx & 127;
    float s = 0.f;
    for (int k = 0; k < 128; ++k) s += U[i*128+k] * V[k*128+j];
    G[idx] = s;
}

__global__ void pre3_kernel(const float* __restrict__ W_nl1, const float* __restrict__ W_el,
                            const float* __restrict__ b_nl1, const float* __restrict__ b_el,
                            const float* __restrict__ G, const float* __restrict__ V,
                            const float* __restrict__ be,
                            float* __restrict__ P, float* __restrict__ Q,
                            float* __restrict__ r) {
    int idx = blockIdx.x * 256 + threadIdx.x;
    if (idx < 16384) {                      // P = W_nl1@G
        int i = idx >> 7, j = idx & 127;
        float s = 0.f;
        for (int k = 0; k < 64; ++k) s += W_nl1[i*64+k] * G[k*128+j];
        P[idx] = s;
    } else if (idx < 32768) {               // Q = W_el@G
        int t = idx - 16384; int i = t >> 7, j = t & 127;
        float s = 0.f;
        for (int k = 0; k < 64; ++k) s += W_el[i*64+k] * G[k*128+j];
        Q[t] = s;
    } else if (idx < 32896) {               // r = (b_nl1+b_el)@G + be@V
        int j = idx - 32768;
        float s = 0.f;
        for (int k = 0; k < 64; ++k)  s += (b_nl1[k] + b_el[k]) * G[k*128+j];
        for (int k = 0; k < 128; ++k) s += be[k] * V[k*128+j];
        r[j] = s;
    }
}

// ---------------- CSR build ----------------
__global__ __launch_bounds__(256) void hist_kernel(const int* __restrict__ dst,
                                                   int* __restrict__ cnt) {
    int e = blockIdx.x * 256 + threadIdx.x;
    if (e < N_EDGES) atomicAdd(&cnt[dst[e]], 1);
}

__global__ __launch_bounds__(256) void scan_a_kernel(const int* __restrict__ cnt,
                                                     int* __restrict__ bsum) {
    __shared__ int s[256];
    int i = blockIdx.x * 256 + threadIdx.x;
    int v = (i < N_NODES) ? cnt[i] : 0;
    s[threadIdx.x] = v;
    __syncthreads();
    for (int d = 128; d > 0; d >>= 1) {
        if (threadIdx.x < d) s[threadIdx.x] += s[threadIdx.x + d];
        __syncthreads();
    }
    if (threadIdx.x == 0) bsum[blockIdx.x] = s[0];
}

__global__ __launch_bounds__(256) void scan_b_kernel(const int* __restrict__ bsum,
                                                     int* __restrict__ boff) {
    __shared__ int s[256];
    int t = threadIdx.x;
    int v = (t < NBLK_SCAN) ? bsum[t] : 0;
    s[t] = v;
    __syncthreads();
    for (int d = 1; d < 256; d <<= 1) {
        int tv = (t >= d) ? s[t - d] : 0;
        __syncthreads();
        s[t] += tv;
        __syncthreads();
    }
    if (t < NBLK_SCAN) boff[t] = s[t] - v;   // exclusive
}

__global__ __launch_bounds__(256) void scan_c_kernel(const int* __restrict__ cnt,
                                                     const int* __restrict__ boff,
                                                     int* __restrict__ offs,
                                                     int* __restrict__ cursor) {
    __shared__ int s[256];
    int i = blockIdx.x * 256 + threadIdx.x;
    int t = threadIdx.x;
    int v = (i < N_NODES) ? cnt[i] : 0;
    s[t] = v;
    __syncthreads();
    for (int d = 1; d < 256; d <<= 1) {
        int tv = (t >= d) ? s[t - d] : 0;
        __syncthreads();
        s[t] += tv;
        __syncthreads();
    }
    if (i < N_NODES) {
        int ex = s[t] - v + boff[blockIdx.x];
        offs[i] = ex;
        cursor[i] = ex;
    }
}

__global__ __launch_bounds__(256) void fill_kernel(const int* __restrict__ dst,
                                                   int* __restrict__ cursor,
                                                   int* __restrict__ eids) {
    int e = blockIdx.x * 256 + threadIdx.x;
    if (e < N_EDGES) {
        int pos = atomicAdd(&cursor[dst[e]], 1);
        eids[pos] = e;
    }
}

// ---------------- gather: xs[n] = sum x[src], es[n] = sum e  (no atomics) --------
// Two half-waves per node; each handles 64 columns (1 float/lane). Edge loop
// unrolled x4 so >=8 independent 256B loads are in flight per wave.
__global__ __launch_bounds__(256) void gather_kernel(
        const float* __restrict__ x, const float* __restrict__ ef,
        const int* __restrict__ src,
        const int* __restrict__ cnt, const int* __restrict__ offs,
        const int* __restrict__ eids,
        float* __restrict__ xs, float* __restrict__ es) {
    int gw   = (int)((blockIdx.x * 256 + threadIdx.x) >> 6);
    int lane = threadIdx.x & 63;
    int n    = gw >> 1;
    int half = gw & 1;
    if (n >= N_NODES) return;
    int col = half * 64 + lane;
    int off = offs[n], deg = cnt[n];
    float ax = 0.f, ae = 0.f;
    for (int c0 = 0; c0 < deg; c0 += 64) {
        int j = c0 + lane;
        int myeid = (j < deg) ? eids[off + j] : 0;
        int mysrc = src[myeid];
        int m = deg - c0; if (m > 64) m = 64;
        int j2 = 0;
        for (; j2 + 4 <= m; j2 += 4) {
            int e0 = __shfl(myeid, j2),   e1 = __shfl(myeid, j2+1),
                e2 = __shfl(myeid, j2+2), e3 = __shfl(myeid, j2+3);
            int s0 = __shfl(mysrc, j2),   s1 = __shfl(mysrc, j2+1),
                s2 = __shfl(mysrc, j2+2), s3 = __shfl(mysrc, j2+3);
            float x0 = x[(size_t)s0*128 + col], x1 = x[(size_t)s1*128 + col],
                  x2 = x[(size_t)s2*128 + col], x3 = x[(size_t)s3*128 + col];
            float f0 = ef[(size_t)e0*128 + col], f1 = ef[(size_t)e1*128 + col],
                  f2 = ef[(size_t)e2*128 + col], f3 = ef[(size_t)e3*128 + col];
            ax += x0 + x1 + x2 + x3;
            ae += f0 + f1 + f2 + f3;
        }
        for (; j2 < m; ++j2) {
            int e0 = __shfl(myeid, j2);
            int s0 = __shfl(mysrc, j2);
            ax += x[(size_t)s0*128 + col];
            ae += ef[(size_t)e0*128 + col];
        }
    }
    xs[(size_t)n*128 + col] = ax;
    es[(size_t)n*128 + col] = ae;
}

// ---------------- output GEMM: out = [x|xs|es] @ [C1;P;Q] + deg*r + c2 ----------
// Block 256 thr, tile 64 rows x 128 cols, K chunks of 32.
// LDS: As[32][65] transposed A-chunk (+1 pad), Ws[32][128] W-chunk. 25 KB.
// Thread: 8 rows x 4 cols. Per k: 2 broadcast b128 (A) + 1 b128 (W), 32 FMA.
__global__ __launch_bounds__(256) void out_gemm_kernel(
        const float* __restrict__ x, const float* __restrict__ xs,
        const float* __restrict__ es, const int* __restrict__ cnt,
        const float* __restrict__ C1, const float* __restrict__ P,
        const float* __restrict__ Q,
        const float* __restrict__ rvec, const float* __restrict__ c2,
        float* __restrict__ out) {
    __shared__ float As[32][65];
    __shared__ float Ws[32][128];
    int base = blockIdx.x * 64;
    int t = threadIdx.x;
    int c0 = (t & 31) * 4;
    int r0 = (t >> 5) * 8;

    float4 rv = *(const float4*)&rvec[c0];
    float4 cv = *(const float4*)&c2[c0];
    float acc[8][4];
    #pragma unroll
    for (int i = 0; i < 8; ++i) {
        int n = base + r0 + i;
        float dg = (n < N_NODES) ? (float)cnt[n] : 0.f;
        acc[i][0] = cv.x + dg * rv.x;
        acc[i][1] = cv.y + dg * rv.y;
        acc[i][2] = cv.z + dg * rv.z;
        acc[i][3] = cv.w + dg * rv.w;
    }

    int kk   = t & 31;          // k within chunk (A stage)
    int rb   = t >> 5;          // row base 0..7 (A stage, stride 8)
    #pragma unroll
    for (int m = 0; m < 3; ++m) {
        const float* __restrict__ S = (m == 0) ? x : (m == 1) ? xs : es;
        const float* __restrict__ W = (m == 0) ? C1 : (m == 1) ? P : Q;
        for (int k0 = 0; k0 < 128; k0 += 32) {
            __syncthreads();
            // stage A^T chunk: As[kk][row]
            #pragma unroll
            for (int i = 0; i < 8; ++i) {
                int row = rb + i * 8;
                int n = base + row;
                As[kk][row] = (n < N_NODES) ? S[(size_t)n * 128 + k0 + kk] : 0.f;
            }
            // stage W chunk: Ws[kw][c]  (32 rows x 32 float4)
            for (int i = t; i < 32 * 32; i += 256) {
                int row = i >> 5, q4 = i & 31;
                *(float4*)&Ws[row][q4 * 4] =
                    *(const float4*)&W[(size_t)(k0 + row) * 128 + q4 * 4];
            }
            __syncthreads();
            #pragma unroll 4
            for (int k = 0; k < 32; ++k) {
                float a[8];
                *(float4*)&a[0] = *(const float4*)&As[k][r0];
                *(float4*)&a[4] = *(const float4*)&As[k][r0 + 4];
                float4 w = *(const float4*)&Ws[k][c0];
                #pragma unroll
                for (int i = 0; i < 8; ++i) {
                    acc[i][0] += a[i] * w.x;
                    acc[i][1] += a[i] * w.y;
                    acc[i][2] += a[i] * w.z;
                    acc[i][3] += a[i] * w.w;
                }
            }
        }
    }

    #pragma unroll
    for (int i = 0; i < 8; ++i) {
        int n = base + r0 + i;
        if (n < N_NODES)
            *(float4*)&out[(size_t)n * 128 + c0] = *(float4*)&acc[i][0];
    }
}

extern "C" void kernel_launch(void* const* d_in, const int* in_sizes, int n_in,
                              void* d_out, int out_size, void* d_ws, size_t ws_size,
                              hipStream_t stream) {
    const float* x     = (const float*)d_in[0];
    const float* ef    = (const float*)d_in[1];
    const int*   src   = (const int*)d_in[2];
    const int*   dst   = (const int*)d_in[3];
    const float* W_nl1 = (const float*)d_in[4];
    const float* b_nl1 = (const float*)d_in[5];
    const float* W_el  = (const float*)d_in[6];
    const float* b_el  = (const float*)d_in[7];
    const float* W1    = (const float*)d_in[8];
    const float* b1    = (const float*)d_in[9];
    const float* W2    = (const float*)d_in[10];
    const float* b2    = (const float*)d_in[11];
    const float* W_nl2 = (const float*)d_in[12];
    const float* b_nl2 = (const float*)d_in[13];
    const float* W_ml  = (const float*)d_in[14];
    const float* b_ml  = (const float*)d_in[15];
    const float* W_em  = (const float*)d_in[16];
    const float* b_em  = (const float*)d_in[17];

    int*   wsI = (int*)d_ws;
    float* wsF = (float*)d_ws;
    float* xs     = wsF + WF_XS;
    float* es     = wsF + WF_ES;
    int*   cnt    = wsI + WI_CNT;
    int*   offs   = wsI + WI_OFF;
    int*   cursor = wsI + WI_CUR;
    int*   bsum   = wsI + WI_BSUM;
    int*   boff   = wsI + WI_BOFF;
    int*   eids   = wsI + WI_EIDS;
    float* U  = wsF + WF_U;
    float* V  = wsF + WF_V;
    float* G  = wsF + WF_G;
    float* P  = wsF + WF_P;
    float* Q  = wsF + WF_Q;
    float* C1 = wsF + WF_C1;
    float* be = wsF + WF_BE;
    float* r  = wsF + WF_R;
    float* c2 = wsF + WF_C2;

    hipMemsetAsync(cnt, 0, N_NODES * sizeof(int), stream);

    pre1_kernel<<<(41216 + 255) / 256, 256, 0, stream>>>(
        W1, W2, b1, b2, W_ml, W_em, W_nl2, b_nl2, b_ml, b_em, U, V, C1, be, c2);
    pre2_kernel<<<8192 / 256, 256, 0, stream>>>(U, V, G);
    pre3_kernel<<<(32896 + 255) / 256, 256, 0, stream>>>(
        W_nl1, W_el, b_nl1, b_el, G, V, be, P, Q, r);

    hist_kernel<<<(N_EDGES + 255) / 256, 256, 0, stream>>>(dst, cnt);
    scan_a_kernel<<<NBLK_SCAN, 256, 0, stream>>>(cnt, bsum);
    scan_b_kernel<<<1, 256, 0, stream>>>(bsum, boff);
    scan_c_kernel<<<NBLK_SCAN, 256, 0, stream>>>(cnt, boff, offs, cursor);
    fill_kernel<<<(N_EDGES + 255) / 256, 256, 0, stream>>>(dst, cursor, eids);

    // gather (100k half-waves = 25000 blocks)
    gather_kernel<<<(N_NODES * 2 + 3) / 4, 256, 0, stream>>>(
        x, ef, src, cnt, offs, eids, xs, es);

    // output GEMM
    out_gemm_kernel<<<(N_NODES + 63) / 64, 256, 0, stream>>>(
        x, xs, es, cnt, C1, P, Q, r, c2, (float*)d_out);
}

// Round 4
// 285.339 us; speedup vs baseline: 4.0678x; 1.1559x over previous
//
#include <hip/hip_runtime.h>

#define N_NODES 50000
#define N_EDGES 600000
// feature dims: IN=128, HID=64, OUT=128

// ---------------- workspace layout ----------------
// floats first: xs, es
#define WF_XS   0            // 6,400,000 floats
#define WF_ES   6400000      // 6,400,000 floats
// ints (element offsets into (int*)d_ws)
#define WI_CNT   12800000    // 50000
#define WI_OFF   12850000    // 50000
#define WI_CUR   12900000    // 50000
#define WI_BSUM  12950000    // 256
#define WI_BOFF  12950256    // 256
#define WI_EPAIR 12950512    // int2 x 600000 = 1,200,000 ints -> ends 14150512
// small float region
#define WF_U    14160000     // 64*128  = 8192
#define WF_V    14168192     // 128*128 = 16384
#define WF_G    14184576     // 8192
#define WF_P    14192768     // 16384
#define WF_Q    14209152     // 16384
#define WF_C1   14225536     // 16384
#define WF_BE   14241920     // 128
#define WF_R    14242048     // 128
#define WF_C2   14242176     // 128
// total ~14.25M elems * 4B = 57 MB

#define NBLK_SCAN 196        // ceil(50000/256)

// ---------------- small fused-matrix precompute ----------------
__global__ void pre1_kernel(const float* __restrict__ W1, const float* __restrict__ W2,
                            const float* __restrict__ b1, const float* __restrict__ b2,
                            const float* __restrict__ W_ml, const float* __restrict__ W_em,
                            const float* __restrict__ W_nl2, const float* __restrict__ b_nl2,
                            const float* __restrict__ b_ml, const float* __restrict__ b_em,
                            float* __restrict__ U, float* __restrict__ V,
                            float* __restrict__ C1, float* __restrict__ be,
                            float* __restrict__ c2) {
    int idx = blockIdx.x * 256 + threadIdx.x;
    if (idx < 8192) {                       // U[64][128] = W1@W2
        int i = idx >> 7, j = idx & 127;
        float s = 0.f;
        for (int k = 0; k < 64; ++k) s += W1[i*64+k] * W2[k*128+j];
        U[idx] = s;
    } else if (idx < 24576) {               // V[128][128] = W_ml@W_em
        int t = idx - 8192; int i = t >> 7, j = t & 127;
        float s = 0.f;
        for (int k = 0; k < 64; ++k) s += W_ml[i*64+k] * W_em[k*128+j];
        V[t] = s;
    } else if (idx < 40960) {               // C1[128][128] = W_nl2@W_em
        int t = idx - 24576; int i = t >> 7, j = t & 127;
        float s = 0.f;
        for (int k = 0; k < 64; ++k) s += W_nl2[i*64+k] * W_em[k*128+j];
        C1[t] = s;
    } else if (idx < 41088) {               // be[128] = b1@W2 + b2
        int j = idx - 40960;
        float s = b2[j];
        for (int k = 0; k < 64; ++k) s += b1[k] * W2[k*128+j];
        be[j] = s;
    } else if (idx < 41216) {               // c2[128] = (b_nl2+b_ml)@W_em + b_em
        int j = idx - 41088;
        float s = b_em[j];
        for (int k = 0; k < 64; ++k) s += (b_nl2[k] + b_ml[k]) * W_em[k*128+j];
        c2[j] = s;
    }
}

__global__ void pre2_kernel(const float* __restrict__ U, const float* __restrict__ V,
                            float* __restrict__ G) {
    int idx = blockIdx.x * 256 + threadIdx.x;
    if (idx >= 8192) return;
    int i = idx >> 7, j = idx & 127;
    float s = 0.f;
    for (int k = 0; k < 128; ++k) s += U[i*128+k] * V[k*128+j];
    G[idx] = s;
}

__global__ void pre3_kernel(const float* __restrict__ W_nl1, const float* __restrict__ W_el,
                            const float* __restrict__ b_nl1, const float* __restrict__ b_el,
                            const float* __restrict__ G, const float* __restrict__ V,
                            const float* __restrict__ be,
                            float* __restrict__ P, float* __restrict__ Q,
                            float* __restrict__ r) {
    int idx = blockIdx.x * 256 + threadIdx.x;
    if (idx < 16384) {                      // P = W_nl1@G
        int i = idx >> 7, j = idx & 127;
        float s = 0.f;
        for (int k = 0; k < 64; ++k) s += W_nl1[i*64+k] * G[k*128+j];
        P[idx] = s;
    } else if (idx < 32768) {               // Q = W_el@G
        int t = idx - 16384; int i = t >> 7, j = t & 127;
        float s = 0.f;
        for (int k = 0; k < 64; ++k) s += W_el[i*64+k] * G[k*128+j];
        Q[t] = s;
    } else if (idx < 32896) {               // r = (b_nl1+b_el)@G + be@V
        int j = idx - 32768;
        float s = 0.f;
        for (int k = 0; k < 64; ++k)  s += (b_nl1[k] + b_el[k]) * G[k*128+j];
        for (int k = 0; k < 128; ++k) s += be[k] * V[k*128+j];
        r[j] = s;
    }
}

// ---------------- CSR build ----------------
__global__ __launch_bounds__(256) void zero_kernel(int* __restrict__ cnt) {
    int i = blockIdx.x * 256 + threadIdx.x;
    if (i < N_NODES) cnt[i] = 0;
}

__global__ __launch_bounds__(256) void hist_kernel(const int* __restrict__ dst,
                                                   int* __restrict__ cnt) {
    int e = blockIdx.x * 256 + threadIdx.x;
    if (e < N_EDGES) atomicAdd(&cnt[dst[e]], 1);
}

__global__ __launch_bounds__(256) void scan_a_kernel(const int* __restrict__ cnt,
                                                     int* __restrict__ bsum) {
    __shared__ int s[256];
    int i = blockIdx.x * 256 + threadIdx.x;
    int v = (i < N_NODES) ? cnt[i] : 0;
    s[threadIdx.x] = v;
    __syncthreads();
    for (int d = 128; d > 0; d >>= 1) {
        if (threadIdx.x < d) s[threadIdx.x] += s[threadIdx.x + d];
        __syncthreads();
    }
    if (threadIdx.x == 0) bsum[blockIdx.x] = s[0];
}

__global__ __launch_bounds__(256) void scan_b_kernel(const int* __restrict__ bsum,
                                                     int* __restrict__ boff) {
    __shared__ int s[256];
    int t = threadIdx.x;
    int v = (t < NBLK_SCAN) ? bsum[t] : 0;
    s[t] = v;
    __syncthreads();
    for (int d = 1; d < 256; d <<= 1) {
        int tv = (t >= d) ? s[t - d] : 0;
        __syncthreads();
        s[t] += tv;
        __syncthreads();
    }
    if (t < NBLK_SCAN) boff[t] = s[t] - v;   // exclusive
}

__global__ __launch_bounds__(256) void scan_c_kernel(const int* __restrict__ cnt,
                                                     const int* __restrict__ boff,
                                                     int* __restrict__ offs,
                                                     int* __restrict__ cursor) {
    __shared__ int s[256];
    int i = blockIdx.x * 256 + threadIdx.x;
    int t = threadIdx.x;
    int v = (i < N_NODES) ? cnt[i] : 0;
    s[t] = v;
    __syncthreads();
    for (int d = 1; d < 256; d <<= 1) {
        int tv = (t >= d) ? s[t - d] : 0;
        __syncthreads();
        s[t] += tv;
        __syncthreads();
    }
    if (i < N_NODES) {
        int ex = s[t] - v + boff[blockIdx.x];
        offs[i] = ex;
        cursor[i] = ex;
    }
}

// fill packed (eid, src[eid]) pairs sorted by dst — removes the dependent
// src-gather from the gather hot loop.
__global__ __launch_bounds__(256) void fill_kernel(const int* __restrict__ dst,
                                                   const int* __restrict__ src,
                                                   int* __restrict__ cursor,
                                                   int2* __restrict__ epair) {
    int e = blockIdx.x * 256 + threadIdx.x;
    if (e < N_EDGES) {
        int pos = atomicAdd(&cursor[dst[e]], 1);
        epair[pos] = make_int2(e, src[e]);
    }
}

// ---------------- gather: xs[n] = sum x[src], es[n] = sum e  (no atomics) --------
// One wave per node, float2 per lane (512B per load inst). Unroll x8 -> 16
// independent 512B loads in flight per wave.
__global__ __launch_bounds__(256) void gather_kernel(
        const float* __restrict__ x, const float* __restrict__ ef,
        const int* __restrict__ cnt, const int* __restrict__ offs,
        const int2* __restrict__ epair,
        float* __restrict__ xs, float* __restrict__ es) {
    int n    = (int)((blockIdx.x * 256 + threadIdx.x) >> 6);
    int lane = threadIdx.x & 63;
    if (n >= N_NODES) return;
    int off = offs[n], deg = cnt[n];
    int col2 = lane * 2;
    float ax0 = 0.f, ax1 = 0.f, ae0 = 0.f, ae1 = 0.f;
    for (int c0 = 0; c0 < deg; c0 += 64) {
        int j = c0 + lane;
        int2 p = make_int2(0, 0);
        if (j < deg) p = epair[off + j];
        int m = deg - c0; if (m > 64) m = 64;
        int j2 = 0;
        for (; j2 + 8 <= m; j2 += 8) {
            float2 xv[8], ev[8];
            #pragma unroll
            for (int u = 0; u < 8; ++u) {
                int e_ = __shfl(p.x, j2 + u);
                int s_ = __shfl(p.y, j2 + u);
                xv[u] = *(const float2*)(x  + (size_t)s_ * 128 + col2);
                ev[u] = *(const float2*)(ef + (size_t)e_ * 128 + col2);
            }
            #pragma unroll
            for (int u = 0; u < 8; ++u) {
                ax0 += xv[u].x; ax1 += xv[u].y;
                ae0 += ev[u].x; ae1 += ev[u].y;
            }
        }
        for (; j2 < m; ++j2) {
            int e_ = __shfl(p.x, j2);
            int s_ = __shfl(p.y, j2);
            float2 xv = *(const float2*)(x  + (size_t)s_ * 128 + col2);
            float2 ev = *(const float2*)(ef + (size_t)e_ * 128 + col2);
            ax0 += xv.x; ax1 += xv.y;
            ae0 += ev.x; ae1 += ev.y;
        }
    }
    *(float2*)(xs + (size_t)n * 128 + col2) = make_float2(ax0, ax1);
    *(float2*)(es + (size_t)n * 128 + col2) = make_float2(ae0, ae1);
}

// ---------------- output GEMM: out = [x|xs|es] @ [C1;P;Q] + deg*r + c2 ----------
// Block 256 thr, tile 128 rows x 128 cols, K chunks of 32.
// LDS: As[32][133] transposed A-chunk (pitch 133 -> conflict-free transpose
// writes: bank = (5k+row)%32), Ws[32][128]. 33 KB -> 4 blocks/CU.
// Thread: 8 rows x 8 cols = 64 acc; per k: 4x ds_read_b128, 64 FMA.
__global__ __launch_bounds__(256) void out_gemm_kernel(
        const float* __restrict__ x, const float* __restrict__ xs,
        const float* __restrict__ es, const int* __restrict__ cnt,
        const float* __restrict__ C1, const float* __restrict__ P,
        const float* __restrict__ Q,
        const float* __restrict__ rvec, const float* __restrict__ c2,
        float* __restrict__ out) {
    __shared__ float As[32][133];
    __shared__ float Ws[32][128];
    int base = blockIdx.x * 128;
    int t = threadIdx.x;
    int cg = t & 15, rg = t >> 4;
    int c0 = cg * 8, r0 = rg * 8;

    float4 rva = *(const float4*)&rvec[c0];
    float4 rvb = *(const float4*)&rvec[c0 + 4];
    float4 cva = *(const float4*)&c2[c0];
    float4 cvb = *(const float4*)&c2[c0 + 4];
    float acc[8][8];
    #pragma unroll
    for (int i = 0; i < 8; ++i) {
        int n = base + r0 + i;
        float dg = (n < N_NODES) ? (float)cnt[n] : 0.f;
        acc[i][0] = cva.x + dg * rva.x;  acc[i][1] = cva.y + dg * rva.y;
        acc[i][2] = cva.z + dg * rva.z;  acc[i][3] = cva.w + dg * rva.w;
        acc[i][4] = cvb.x + dg * rvb.x;  acc[i][5] = cvb.y + dg * rvb.y;
        acc[i][6] = cvb.z + dg * rvb.z;  acc[i][7] = cvb.w + dg * rvb.w;
    }

    // staging index decomposition (A): 1024 float4 = 128 rows x 8 k-quads
    int arow0 = t >> 3;          // 0..31, +32 per iter
    int akq   = t & 7;           // k-quad 0..7 (32 k per chunk)

    #pragma unroll
    for (int m = 0; m < 3; ++m) {
        const float* __restrict__ S = (m == 0) ? x : (m == 1) ? xs : es;
        const float* __restrict__ W = (m == 0) ? C1 : (m == 1) ? P : Q;
        for (int k0 = 0; k0 < 128; k0 += 32) {
            __syncthreads();
            // stage A^T chunk (transposed): As[k][row]
            #pragma unroll
            for (int i = 0; i < 4; ++i) {
                int row = arow0 + i * 32;
                int n = base + row;
                float4 v = make_float4(0.f, 0.f, 0.f, 0.f);
                if (n < N_NODES)
                    v = *(const float4*)&S[(size_t)n * 128 + k0 + akq * 4];
                As[akq * 4 + 0][row] = v.x;
                As[akq * 4 + 1][row] = v.y;
                As[akq * 4 + 2][row] = v.z;
                As[akq * 4 + 3][row] = v.w;
            }
            // stage W chunk: Ws[k][c], 1024 float4 over 256 threads
            #pragma unroll
            for (int i = 0; i < 4; ++i) {
                int idx = t + i * 256;
                int row = idx >> 5, q4 = idx & 31;
                *(float4*)&Ws[row][q4 * 4] =
                    *(const float4*)&W[(size_t)(k0 + row) * 128 + q4 * 4];
            }
            __syncthreads();
            #pragma unroll 8
            for (int k = 0; k < 32; ++k) {
                float a[8], w[8];
                *(float4*)&a[0] = *(const float4*)&As[k][r0];
                *(float4*)&a[4] = *(const float4*)&As[k][r0 + 4];
                *(float4*)&w[0] = *(const float4*)&Ws[k][c0];
                *(float4*)&w[4] = *(const float4*)&Ws[k][c0 + 4];
                #pragma unroll
                for (int i = 0; i < 8; ++i)
                    #pragma unroll
                    for (int jj = 0; jj < 8; ++jj)
                        acc[i][jj] += a[i] * w[jj];
            }
        }
    }

    #pragma unroll
    for (int i = 0; i < 8; ++i) {
        int n = base + r0 + i;
        if (n < N_NODES) {
            *(float4*)&out[(size_t)n * 128 + c0]     = *(float4*)&acc[i][0];
            *(float4*)&out[(size_t)n * 128 + c0 + 4] = *(float4*)&acc[i][4];
        }
    }
}

extern "C" void kernel_launch(void* const* d_in, const int* in_sizes, int n_in,
                              void* d_out, int out_size, void* d_ws, size_t ws_size,
                              hipStream_t stream) {
    const float* x     = (const float*)d_in[0];
    const float* ef    = (const float*)d_in[1];
    const int*   src   = (const int*)d_in[2];
    const int*   dst   = (const int*)d_in[3];
    const float* W_nl1 = (const float*)d_in[4];
    const float* b_nl1 = (const float*)d_in[5];
    const float* W_el  = (const float*)d_in[6];
    const float* b_el  = (const float*)d_in[7];
    const float* W1    = (const float*)d_in[8];
    const float* b1    = (const float*)d_in[9];
    const float* W2    = (const float*)d_in[10];
    const float* b2    = (const float*)d_in[11];
    const float* W_nl2 = (const float*)d_in[12];
    const float* b_nl2 = (const float*)d_in[13];
    const float* W_ml  = (const float*)d_in[14];
    const float* b_ml  = (const float*)d_in[15];
    const float* W_em  = (const float*)d_in[16];
    const float* b_em  = (const float*)d_in[17];

    int*   wsI = (int*)d_ws;
    float* wsF = (float*)d_ws;
    float* xs     = wsF + WF_XS;
    float* es     = wsF + WF_ES;
    int*   cnt    = wsI + WI_CNT;
    int*   offs   = wsI + WI_OFF;
    int*   cursor = wsI + WI_CUR;
    int*   bsum   = wsI + WI_BSUM;
    int*   boff   = wsI + WI_BOFF;
    int2*  epair  = (int2*)(wsI + WI_EPAIR);
    float* U  = wsF + WF_U;
    float* V  = wsF + WF_V;
    float* G  = wsF + WF_G;
    float* P  = wsF + WF_P;
    float* Q  = wsF + WF_Q;
    float* C1 = wsF + WF_C1;
    float* be = wsF + WF_BE;
    float* r  = wsF + WF_R;
    float* c2 = wsF + WF_C2;

    zero_kernel<<<NBLK_SCAN, 256, 0, stream>>>(cnt);

    pre1_kernel<<<(41216 + 255) / 256, 256, 0, stream>>>(
        W1, W2, b1, b2, W_ml, W_em, W_nl2, b_nl2, b_ml, b_em, U, V, C1, be, c2);
    pre2_kernel<<<8192 / 256, 256, 0, stream>>>(U, V, G);
    pre3_kernel<<<(32896 + 255) / 256, 256, 0, stream>>>(
        W_nl1, W_el, b_nl1, b_el, G, V, be, P, Q, r);

    hist_kernel<<<(N_EDGES + 255) / 256, 256, 0, stream>>>(dst, cnt);
    scan_a_kernel<<<NBLK_SCAN, 256, 0, stream>>>(cnt, bsum);
    scan_b_kernel<<<1, 256, 0, stream>>>(bsum, boff);
    scan_c_kernel<<<NBLK_SCAN, 256, 0, stream>>>(cnt, boff, offs, cursor);
    fill_kernel<<<(N_EDGES + 255) / 256, 256, 0, stream>>>(dst, src, cursor, epair);

    // gather: one wave per node -> 50000 waves, 4 per block
    gather_kernel<<<(N_NODES + 3) / 4, 256, 0, stream>>>(
        x, ef, cnt, offs, epair, xs, es);

    // output GEMM: 128-row tiles
    out_gemm_kernel<<<(N_NODES + 127) / 128, 256, 0, stream>>>(
        x, xs, es, cnt, C1, P, Q, r, c2, (float*)d_out);
}

// Round 6
// 278.938 us; speedup vs baseline: 4.1612x; 1.0230x over previous
//
#include <hip/hip_runtime.h>

#define N_NODES 50000
#define N_EDGES 600000
// feature dims: IN=128, HID=64, OUT=128

// ---------------- workspace layout ----------------
// floats: xs, es, u
#define WF_XS   0            // 6,400,000 floats
#define WF_ES   6400000      // 6,400,000 floats
#define WF_UN   12800000     // u: N*64 = 3,200,000 -> ends 16,000,000
// ints (element offsets into (int*)d_ws)
#define WI_CNT   16000000    // 50000
#define WI_OFF   16050000    // 50000
#define WI_CUR   16100000    // 50000
#define WI_BSUM  16150000    // 256
#define WI_BOFF  16150256    // 256
#define WI_EPAIR 16150512    // int2 x 600000 = 1,200,000 ints -> ends 17,350,512
// small float region (byte-aligned fine; all 4B elems)
#define WF_T2   17350528     // 64*64 = 4096
#define WF_BEG  17354624     // 128
#define WF_RH   17354752     // 64
#define WF_K1   17354816     // 64*64 = 4096
#define WF_WA   17358912     // 384*64 = 24576 -> 17383488
#define WF_R    17383488     // 128
#define WF_C2   17383616     // 128 -> ends 17383744 (~69.5 MB)

#define NBLK_SCAN 196        // ceil(50000/256)

// ---------------- precompute chain (global-staged, no __shared__) ----------------
// pre_t2: T2 = W2@W_ml [64,64]; be = b1@W2 + b2 [128]
__global__ __launch_bounds__(256) void pre_t2_kernel(
        const float* __restrict__ W2, const float* __restrict__ W_ml,
        const float* __restrict__ b1, const float* __restrict__ b2,
        float* __restrict__ T2, float* __restrict__ be_g) {
    int idx = blockIdx.x * 256 + threadIdx.x;
    if (idx < 4096) {
        int i = idx >> 6, j = idx & 63;
        float s = 0.f;
        for (int k = 0; k < 128; ++k) s += W2[i*128+k] * W_ml[k*64+j];
        T2[idx] = s;
    } else if (idx < 4224) {
        int j = idx - 4096;
        float s = b2[j];
        for (int k = 0; k < 64; ++k) s += b1[k] * W2[k*128+j];
        be_g[j] = s;
    }
}

// pre_k1: K1 = W1@T2 [64,64]
__global__ __launch_bounds__(256) void pre_k1_kernel(
        const float* __restrict__ W1, const float* __restrict__ T2,
        float* __restrict__ K1) {
    int idx = blockIdx.x * 256 + threadIdx.x;
    if (idx >= 4096) return;
    int i = idx >> 6, j = idx & 63;
    float s = 0.f;
    for (int k = 0; k < 64; ++k) s += W1[i*64+k] * T2[k*64+j];
    K1[idx] = s;
}

// pre_wa: WA = [W_nl2 ; W_nl1@K1 ; W_el@K1] [384,64]; rh = (b_nl1+b_el)@K1 + be@W_ml
__global__ __launch_bounds__(256) void pre_wa_kernel(
        const float* __restrict__ W_nl1, const float* __restrict__ W_el,
        const float* __restrict__ W_nl2, const float* __restrict__ K1,
        const float* __restrict__ b_nl1, const float* __restrict__ b_el,
        const float* __restrict__ be_g, const float* __restrict__ W_ml,
        float* __restrict__ WA, float* __restrict__ rh_g) {
    int idx = blockIdx.x * 256 + threadIdx.x;
    if (idx < 8192) {
        WA[idx] = W_nl2[idx];
    } else if (idx < 16384) {
        int p = idx - 8192; int i = p >> 6, j = p & 63;
        float s = 0.f;
        for (int k = 0; k < 64; ++k) s += W_nl1[i*64+k] * K1[k*64+j];
        WA[idx] = s;
    } else if (idx < 24576) {
        int p = idx - 16384; int i = p >> 6, j = p & 63;
        float s = 0.f;
        for (int k = 0; k < 64; ++k) s += W_el[i*64+k] * K1[k*64+j];
        WA[idx] = s;
    } else if (idx < 24640) {
        int t = idx - 24576;
        float s = 0.f;
        for (int k = 0; k < 64; ++k)  s += (b_nl1[k] + b_el[k]) * K1[k*64+t];
        for (int k = 0; k < 128; ++k) s += be_g[k] * W_ml[k*64+t];
        rh_g[t] = s;
    }
}

// pre_rc: r = rh@W_em [128]; c2 = (b_nl2+b_ml)@W_em + b_em [128]
__global__ __launch_bounds__(256) void pre_rc_kernel(
        const float* __restrict__ rh_g, const float* __restrict__ W_em,
        const float* __restrict__ b_nl2, const float* __restrict__ b_ml,
        const float* __restrict__ b_em,
        float* __restrict__ r, float* __restrict__ c2) {
    int idx = threadIdx.x;
    if (idx < 128) {
        float s = 0.f;
        for (int k = 0; k < 64; ++k) s += rh_g[k] * W_em[k*128+idx];
        r[idx] = s;
    } else {
        int j = idx - 128;
        float s = b_em[j];
        for (int k = 0; k < 64; ++k) s += (b_nl2[k] + b_ml[k]) * W_em[k*128+j];
        c2[j] = s;
    }
}

// ---------------- CSR build (verbatim R4, proven) ----------------
__global__ __launch_bounds__(256) void zero_kernel(int* __restrict__ cnt) {
    int i = blockIdx.x * 256 + threadIdx.x;
    if (i < N_NODES) cnt[i] = 0;
}

__global__ __launch_bounds__(256) void hist_kernel(const int* __restrict__ dst,
                                                   int* __restrict__ cnt) {
    int e = blockIdx.x * 256 + threadIdx.x;
    if (e < N_EDGES) atomicAdd(&cnt[dst[e]], 1);
}

__global__ __launch_bounds__(256) void scan_a_kernel(const int* __restrict__ cnt,
                                                     int* __restrict__ bsum) {
    __shared__ int s[256];
    int i = blockIdx.x * 256 + threadIdx.x;
    int v = (i < N_NODES) ? cnt[i] : 0;
    s[threadIdx.x] = v;
    __syncthreads();
    for (int d = 128; d > 0; d >>= 1) {
        if (threadIdx.x < d) s[threadIdx.x] += s[threadIdx.x + d];
        __syncthreads();
    }
    if (threadIdx.x == 0) bsum[blockIdx.x] = s[0];
}

__global__ __launch_bounds__(256) void scan_b_kernel(const int* __restrict__ bsum,
                                                     int* __restrict__ boff) {
    __shared__ int s[256];
    int t = threadIdx.x;
    int v = (t < NBLK_SCAN) ? bsum[t] : 0;
    s[t] = v;
    __syncthreads();
    for (int d = 1; d < 256; d <<= 1) {
        int tv = (t >= d) ? s[t - d] : 0;
        __syncthreads();
        s[t] += tv;
        __syncthreads();
    }
    if (t < NBLK_SCAN) boff[t] = s[t] - v;   // exclusive
}

__global__ __launch_bounds__(256) void scan_c_kernel(const int* __restrict__ cnt,
                                                     const int* __restrict__ boff,
                                                     int* __restrict__ offs,
                                                     int* __restrict__ cursor) {
    __shared__ int s[256];
    int i = blockIdx.x * 256 + threadIdx.x;
    int t = threadIdx.x;
    int v = (i < N_NODES) ? cnt[i] : 0;
    s[t] = v;
    __syncthreads();
    for (int d = 1; d < 256; d <<= 1) {
        int tv = (t >= d) ? s[t - d] : 0;
        __syncthreads();
        s[t] += tv;
        __syncthreads();
    }
    if (i < N_NODES) {
        int ex = s[t] - v + boff[blockIdx.x];
        offs[i] = ex;
        cursor[i] = ex;
    }
}

// fill packed (eid, src[eid]) pairs sorted by dst
__global__ __launch_bounds__(256) void fill_kernel(const int* __restrict__ dst,
                                                   const int* __restrict__ src,
                                                   int* __restrict__ cursor,
                                                   int2* __restrict__ epair) {
    int e = blockIdx.x * 256 + threadIdx.x;
    if (e < N_EDGES) {
        int pos = atomicAdd(&cursor[dst[e]], 1);
        epair[pos] = make_int2(e, src[e]);
    }
}

// ---------------- gather (verbatim R4, proven) ----------------
__global__ __launch_bounds__(256) void gather_kernel(
        const float* __restrict__ x, const float* __restrict__ ef,
        const int* __restrict__ cnt, const int* __restrict__ offs,
        const int2* __restrict__ epair,
        float* __restrict__ xs, float* __restrict__ es) {
    int n    = (int)((blockIdx.x * 256 + threadIdx.x) >> 6);
    int lane = threadIdx.x & 63;
    if (n >= N_NODES) return;
    int off = offs[n], deg = cnt[n];
    int col2 = lane * 2;
    float ax0 = 0.f, ax1 = 0.f, ae0 = 0.f, ae1 = 0.f;
    for (int c0 = 0; c0 < deg; c0 += 64) {
        int j = c0 + lane;
        int2 p = make_int2(0, 0);
        if (j < deg) p = epair[off + j];
        int m = deg - c0; if (m > 64) m = 64;
        int j2 = 0;
        for (; j2 + 8 <= m; j2 += 8) {
            float2 xv[8], ev[8];
            #pragma unroll
            for (int u = 0; u < 8; ++u) {
                int e_ = __shfl(p.x, j2 + u);
                int s_ = __shfl(p.y, j2 + u);
                xv[u] = *(const float2*)(x  + (size_t)s_ * 128 + col2);
                ev[u] = *(const float2*)(ef + (size_t)e_ * 128 + col2);
            }
            #pragma unroll
            for (int u = 0; u < 8; ++u) {
                ax0 += xv[u].x; ax1 += xv[u].y;
                ae0 += ev[u].x; ae1 += ev[u].y;
            }
        }
        for (; j2 < m; ++j2) {
            int e_ = __shfl(p.x, j2);
            int s_ = __shfl(p.y, j2);
            float2 xv = *(const float2*)(x  + (size_t)s_ * 128 + col2);
            float2 ev = *(const float2*)(ef + (size_t)e_ * 128 + col2);
            ax0 += xv.x; ax1 += xv.y;
            ae0 += ev.x; ae1 += ev.y;
        }
    }
    *(float2*)(xs + (size_t)n * 128 + col2) = make_float2(ax0, ax1);
    *(float2*)(es + (size_t)n * 128 + col2) = make_float2(ae0, ae1);
}

// ---------------- gemm1: u = [x|xs|es] @ WA   [N,64], K=384 ----------------
__global__ __launch_bounds__(256) void gemm1_kernel(
        const float* __restrict__ x, const float* __restrict__ xs,
        const float* __restrict__ es, const float* __restrict__ WA,
        float* __restrict__ u) {
    __shared__ float As[32][133];
    __shared__ float Ws[32][64];
    int base = blockIdx.x * 128;
    int t = threadIdx.x;
    int cg = t & 15, rg = t >> 4;
    int c0 = cg * 4, r0 = rg * 8;

    float acc[8][4];
    #pragma unroll
    for (int i = 0; i < 8; ++i)
        #pragma unroll
        for (int j = 0; j < 4; ++j) acc[i][j] = 0.f;

    int arow0 = t >> 3;          // 0..31, +32 per iter
    int akq   = t & 7;           // k-quad 0..7

    #pragma unroll
    for (int m = 0; m < 3; ++m) {
        const float* __restrict__ S = (m == 0) ? x : (m == 1) ? xs : es;
        for (int k0 = 0; k0 < 128; k0 += 32) {
            __syncthreads();
            #pragma unroll
            for (int i = 0; i < 4; ++i) {
                int row = arow0 + i * 32;
                int n = base + row;
                float4 v = make_float4(0.f, 0.f, 0.f, 0.f);
                if (n < N_NODES)
                    v = *(const float4*)&S[(size_t)n * 128 + k0 + akq * 4];
                As[akq * 4 + 0][row] = v.x;
                As[akq * 4 + 1][row] = v.y;
                As[akq * 4 + 2][row] = v.z;
                As[akq * 4 + 3][row] = v.w;
            }
            #pragma unroll
            for (int i = 0; i < 2; ++i) {
                int idx = t + i * 256;
                int row = idx >> 4, q4 = idx & 15;
                *(float4*)&Ws[row][q4 * 4] =
                    *(const float4*)&WA[(size_t)(m * 128 + k0 + row) * 64 + q4 * 4];
            }
            __syncthreads();
            #pragma unroll 8
            for (int k = 0; k < 32; ++k) {
                float a[8];
                *(float4*)&a[0] = *(const float4*)&As[k][r0];
                *(float4*)&a[4] = *(const float4*)&As[k][r0 + 4];
                float4 w = *(const float4*)&Ws[k][c0];
                #pragma unroll
                for (int i = 0; i < 8; ++i) {
                    acc[i][0] += a[i] * w.x;
                    acc[i][1] += a[i] * w.y;
                    acc[i][2] += a[i] * w.z;
                    acc[i][3] += a[i] * w.w;
                }
            }
        }
    }

    #pragma unroll
    for (int i = 0; i < 8; ++i) {
        int n = base + r0 + i;
        if (n < N_NODES)
            *(float4*)&u[(size_t)n * 64 + c0] = *(float4*)&acc[i][0];
    }
}

// ---------------- gemm2: out = u @ W_em + deg*r + c2   [N,128], K=64 ----------
__global__ __launch_bounds__(256) void gemm2_kernel(
        const float* __restrict__ u, const int* __restrict__ cnt,
        const float* __restrict__ W_em,
        const float* __restrict__ rvec, const float* __restrict__ c2,
        float* __restrict__ out) {
    __shared__ float UsT[64][69];
    __shared__ float Wem[64][128];
    int base = blockIdx.x * 64;
    int t = threadIdx.x;
    int cg = t & 15, rg = t >> 4;
    int c0 = cg * 8, r0 = rg * 4;

    #pragma unroll
    for (int i = 0; i < 4; ++i) {
        int idx = t + i * 256;
        int row = idx >> 4, kq = idx & 15;
        int n = base + row;
        float4 v = make_float4(0.f, 0.f, 0.f, 0.f);
        if (n < N_NODES) v = *(const float4*)&u[(size_t)n * 64 + kq * 4];
        UsT[kq * 4 + 0][row] = v.x;
        UsT[kq * 4 + 1][row] = v.y;
        UsT[kq * 4 + 2][row] = v.z;
        UsT[kq * 4 + 3][row] = v.w;
    }
    #pragma unroll
    for (int i = 0; i < 8; ++i) {
        int idx = t + i * 256;
        int row = idx >> 5, q4 = idx & 31;
        *(float4*)&Wem[row][q4 * 4] = *(const float4*)&W_em[(size_t)row * 128 + q4 * 4];
    }

    float4 rva = *(const float4*)&rvec[c0];
    float4 rvb = *(const float4*)&rvec[c0 + 4];
    float4 cva = *(const float4*)&c2[c0];
    float4 cvb = *(const float4*)&c2[c0 + 4];
    float acc[4][8];
    #pragma unroll
    for (int i = 0; i < 4; ++i) {
        int n = base + r0 + i;
        float dg = (n < N_NODES) ? (float)cnt[n] : 0.f;
        acc[i][0] = cva.x + dg * rva.x;  acc[i][1] = cva.y + dg * rva.y;
        acc[i][2] = cva.z + dg * rva.z;  acc[i][3] = cva.w + dg * rva.w;
        acc[i][4] = cvb.x + dg * rvb.x;  acc[i][5] = cvb.y + dg * rvb.y;
        acc[i][6] = cvb.z + dg * rvb.z;  acc[i][7] = cvb.w + dg * rvb.w;
    }
    __syncthreads();

    #pragma unroll 8
    for (int k = 0; k < 64; ++k) {
        float a[4], w[8];
        *(float4*)&a[0] = *(const float4*)&UsT[k][r0];
        *(float4*)&w[0] = *(const float4*)&Wem[k][c0];
        *(float4*)&w[4] = *(const float4*)&Wem[k][c0 + 4];
        #pragma unroll
        for (int i = 0; i < 4; ++i)
            #pragma unroll
            for (int j = 0; j < 8; ++j)
                acc[i][j] += a[i] * w[j];
    }

    #pragma unroll
    for (int i = 0; i < 4; ++i) {
        int n = base + r0 + i;
        if (n < N_NODES) {
            *(float4*)&out[(size_t)n * 128 + c0]     = *(float4*)&acc[i][0];
            *(float4*)&out[(size_t)n * 128 + c0 + 4] = *(float4*)&acc[i][4];
        }
    }
}

extern "C" void kernel_launch(void* const* d_in, const int* in_sizes, int n_in,
                              void* d_out, int out_size, void* d_ws, size_t ws_size,
                              hipStream_t stream) {
    const float* x     = (const float*)d_in[0];
    const float* ef    = (const float*)d_in[1];
    const int*   src   = (const int*)d_in[2];
    const int*   dst   = (const int*)d_in[3];
    const float* W_nl1 = (const float*)d_in[4];
    const float* b_nl1 = (const float*)d_in[5];
    const float* W_el  = (const float*)d_in[6];
    const float* b_el  = (const float*)d_in[7];
    const float* W1    = (const float*)d_in[8];
    const float* b1    = (const float*)d_in[9];
    const float* W2    = (const float*)d_in[10];
    const float* b2    = (const float*)d_in[11];
    const float* W_nl2 = (const float*)d_in[12];
    const float* b_nl2 = (const float*)d_in[13];
    const float* W_ml  = (const float*)d_in[14];
    const float* b_ml  = (const float*)d_in[15];
    const float* W_em  = (const float*)d_in[16];
    const float* b_em  = (const float*)d_in[17];

    int*   wsI = (int*)d_ws;
    float* wsF = (float*)d_ws;
    float* xs     = wsF + WF_XS;
    float* es     = wsF + WF_ES;
    float* uN     = wsF + WF_UN;
    int*   cnt    = wsI + WI_CNT;
    int*   offs   = wsI + WI_OFF;
    int*   cursor = wsI + WI_CUR;
    int*   bsum   = wsI + WI_BSUM;
    int*   boff   = wsI + WI_BOFF;
    int2*  epair  = (int2*)(wsI + WI_EPAIR);
    float* T2   = wsF + WF_T2;
    float* be_g = wsF + WF_BEG;
    float* rh_g = wsF + WF_RH;
    float* K1   = wsF + WF_K1;
    float* WA   = wsF + WF_WA;
    float* r    = wsF + WF_R;
    float* c2   = wsF + WF_C2;

    // precompute chain (tiny, global-staged)
    pre_t2_kernel<<<17, 256, 0, stream>>>(W2, W_ml, b1, b2, T2, be_g);
    pre_k1_kernel<<<16, 256, 0, stream>>>(W1, T2, K1);
    pre_wa_kernel<<<97, 256, 0, stream>>>(W_nl1, W_el, W_nl2, K1,
                                          b_nl1, b_el, be_g, W_ml, WA, rh_g);
    pre_rc_kernel<<<1, 256, 0, stream>>>(rh_g, W_em, b_nl2, b_ml, b_em, r, c2);

    // CSR build (proven R4 path)
    zero_kernel<<<NBLK_SCAN, 256, 0, stream>>>(cnt);
    hist_kernel<<<(N_EDGES + 255) / 256, 256, 0, stream>>>(dst, cnt);
    scan_a_kernel<<<NBLK_SCAN, 256, 0, stream>>>(cnt, bsum);
    scan_b_kernel<<<1, 256, 0, stream>>>(bsum, boff);
    scan_c_kernel<<<NBLK_SCAN, 256, 0, stream>>>(cnt, boff, offs, cursor);
    fill_kernel<<<(N_EDGES + 255) / 256, 256, 0, stream>>>(dst, src, cursor, epair);

    // gather: one wave per node
    gather_kernel<<<(N_NODES + 3) / 4, 256, 0, stream>>>(
        x, ef, cnt, offs, epair, xs, es);

    gemm1_kernel<<<(N_NODES + 127) / 128, 256, 0, stream>>>(x, xs, es, WA, uN);
    gemm2_kernel<<<(N_NODES + 63) / 64, 256, 0, stream>>>(
        uN, cnt, W_em, r, c2, (float*)d_out);
}

// Round 7
// 252.204 us; speedup vs baseline: 4.6023x; 1.1060x over previous
//
#include <hip/hip_runtime.h>

#define N_NODES 50000
#define N_EDGES 600000
// feature dims: IN=128, HID=64, OUT=128

typedef float v2f __attribute__((ext_vector_type(2)));

// ---------------- workspace layout ----------------
// floats: px, es, pxs, u
#define WF_PX   0            // N*64 = 3,200,000 floats
#define WF_ES   3200000      // N*128 = 6,400,000
#define WF_PXS  9600000      // N*64 = 3,200,000
#define WF_UN   12800000     // N*64 = 3,200,000 -> ends 16,000,000
// ints (element offsets into (int*)d_ws)
#define WI_CNT   16000000    // 50000
#define WI_OFF   16050000    // 50000
#define WI_CUR   16100000    // 50000
#define WI_BSUM  16150000    // 256
#define WI_BOFF  16150256    // 256
#define WI_EPAIR 16150512    // int2 x 600000 = 1,200,000 ints -> ends 17,350,512
// small float region
#define WF_T2   17350528     // 4096
#define WF_BEG  17354624     // 128
#define WF_RH   17354752     // 64
#define WF_K1   17354816     // 4096
#define WF_WA   17358912     // 256*64 = 16384 -> 17375296
#define WF_WX1  17375296     // 128*64 = 8192  -> 17383488
#define WF_R    17383488     // 128
#define WF_C2   17383616     // 128 -> ends 17383744 (~69.5 MB)

#define NBLK_SCAN 196        // ceil(50000/256)

// ---------------- precompute chain (global-staged) ----------------
// pre_t2: T2 = W2@W_ml [64,64]; be = b1@W2 + b2 [128]
__global__ __launch_bounds__(256) void pre_t2_kernel(
        const float* __restrict__ W2, const float* __restrict__ W_ml,
        const float* __restrict__ b1, const float* __restrict__ b2,
        float* __restrict__ T2, float* __restrict__ be_g) {
    int idx = blockIdx.x * 256 + threadIdx.x;
    if (idx < 4096) {
        int i = idx >> 6, j = idx & 63;
        float s = 0.f;
        for (int k = 0; k < 128; ++k) s += W2[i*128+k] * W_ml[k*64+j];
        T2[idx] = s;
    } else if (idx < 4224) {
        int j = idx - 4096;
        float s = b2[j];
        for (int k = 0; k < 64; ++k) s += b1[k] * W2[k*128+j];
        be_g[j] = s;
    }
}

// pre_k1: K1 = W1@T2 [64,64]
__global__ __launch_bounds__(256) void pre_k1_kernel(
        const float* __restrict__ W1, const float* __restrict__ T2,
        float* __restrict__ K1) {
    int idx = blockIdx.x * 256 + threadIdx.x;
    if (idx >= 4096) return;
    int i = idx >> 6, j = idx & 63;
    float s = 0.f;
    for (int k = 0; k < 64; ++k) s += W1[i*64+k] * T2[k*64+j];
    K1[idx] = s;
}

// pre_wa: WA = [W_nl2 ; W_el@K1] [256,64]; WX1 = W_nl1@K1 [128,64];
//         rh = (b_nl1+b_el)@K1 + be@W_ml [64]
__global__ __launch_bounds__(256) void pre_wa_kernel(
        const float* __restrict__ W_nl1, const float* __restrict__ W_el,
        const float* __restrict__ W_nl2, const float* __restrict__ K1,
        const float* __restrict__ b_nl1, const float* __restrict__ b_el,
        const float* __restrict__ be_g, const float* __restrict__ W_ml,
        float* __restrict__ WA, float* __restrict__ WX1,
        float* __restrict__ rh_g) {
    int idx = blockIdx.x * 256 + threadIdx.x;
    if (idx < 8192) {                       // WA rows 0-127: W_nl2 copy
        WA[idx] = W_nl2[idx];
    } else if (idx < 16384) {               // WA rows 128-255: W_el@K1
        int p = idx - 8192; int i = p >> 6, j = p & 63;
        float s = 0.f;
        for (int k = 0; k < 64; ++k) s += W_el[i*64+k] * K1[k*64+j];
        WA[idx] = s;
    } else if (idx < 24576) {               // WX1 = W_nl1@K1
        int p = idx - 16384; int i = p >> 6, j = p & 63;
        float s = 0.f;
        for (int k = 0; k < 64; ++k) s += W_nl1[i*64+k] * K1[k*64+j];
        WX1[p] = s;
    } else if (idx < 24640) {               // rh
        int t = idx - 24576;
        float s = 0.f;
        for (int k = 0; k < 64; ++k)  s += (b_nl1[k] + b_el[k]) * K1[k*64+t];
        for (int k = 0; k < 128; ++k) s += be_g[k] * W_ml[k*64+t];
        rh_g[t] = s;
    }
}

// pre_rc: r = rh@W_em [128]; c2 = (b_nl2+b_ml)@W_em + b_em [128]
__global__ __launch_bounds__(256) void pre_rc_kernel(
        const float* __restrict__ rh_g, const float* __restrict__ W_em,
        const float* __restrict__ b_nl2, const float* __restrict__ b_ml,
        const float* __restrict__ b_em,
        float* __restrict__ r, float* __restrict__ c2) {
    int idx = threadIdx.x;
    if (idx < 128) {
        float s = 0.f;
        for (int k = 0; k < 64; ++k) s += rh_g[k] * W_em[k*128+idx];
        r[idx] = s;
    } else {
        int j = idx - 128;
        float s = b_em[j];
        for (int k = 0; k < 64; ++k) s += (b_nl2[k] + b_ml[k]) * W_em[k*128+j];
        c2[j] = s;
    }
}

// ---------------- CSR build (proven) ----------------
__global__ __launch_bounds__(256) void zero_kernel(int* __restrict__ cnt) {
    int i = blockIdx.x * 256 + threadIdx.x;
    if (i < N_NODES) cnt[i] = 0;
}

__global__ __launch_bounds__(256) void hist_kernel(const int* __restrict__ dst,
                                                   int* __restrict__ cnt) {
    int e = blockIdx.x * 256 + threadIdx.x;
    if (e < N_EDGES) atomicAdd(&cnt[dst[e]], 1);
}

__global__ __launch_bounds__(256) void scan_a_kernel(const int* __restrict__ cnt,
                                                     int* __restrict__ bsum) {
    __shared__ int s[256];
    int i = blockIdx.x * 256 + threadIdx.x;
    int v = (i < N_NODES) ? cnt[i] : 0;
    s[threadIdx.x] = v;
    __syncthreads();
    for (int d = 128; d > 0; d >>= 1) {
        if (threadIdx.x < d) s[threadIdx.x] += s[threadIdx.x + d];
        __syncthreads();
    }
    if (threadIdx.x == 0) bsum[blockIdx.x] = s[0];
}

__global__ __launch_bounds__(256) void scan_b_kernel(const int* __restrict__ bsum,
                                                     int* __restrict__ boff) {
    __shared__ int s[256];
    int t = threadIdx.x;
    int v = (t < NBLK_SCAN) ? bsum[t] : 0;
    s[t] = v;
    __syncthreads();
    for (int d = 1; d < 256; d <<= 1) {
        int tv = (t >= d) ? s[t - d] : 0;
        __syncthreads();
        s[t] += tv;
        __syncthreads();
    }
    if (t < NBLK_SCAN) boff[t] = s[t] - v;   // exclusive
}

__global__ __launch_bounds__(256) void scan_c_kernel(const int* __restrict__ cnt,
                                                     const int* __restrict__ boff,
                                                     int* __restrict__ offs,
                                                     int* __restrict__ cursor) {
    __shared__ int s[256];
    int i = blockIdx.x * 256 + threadIdx.x;
    int t = threadIdx.x;
    int v = (i < N_NODES) ? cnt[i] : 0;
    s[t] = v;
    __syncthreads();
    for (int d = 1; d < 256; d <<= 1) {
        int tv = (t >= d) ? s[t - d] : 0;
        __syncthreads();
        s[t] += tv;
        __syncthreads();
    }
    if (i < N_NODES) {
        int ex = s[t] - v + boff[blockIdx.x];
        offs[i] = ex;
        cursor[i] = ex;
    }
}

__global__ __launch_bounds__(256) void fill_kernel(const int* __restrict__ dst,
                                                   const int* __restrict__ src,
                                                   int* __restrict__ cursor,
                                                   int2* __restrict__ epair) {
    int e = blockIdx.x * 256 + threadIdx.x;
    if (e < N_EDGES) {
        int pos = atomicAdd(&cursor[dst[e]], 1);
        epair[pos] = make_int2(e, src[e]);
    }
}

// ---------------- px = x @ WX1   [N,64], K=128 ----------------
__global__ __launch_bounds__(256) void px_kernel(
        const float* __restrict__ x, const float* __restrict__ WX1,
        float* __restrict__ px) {
    __shared__ float As[32][133];
    __shared__ float Ws[32][64];
    int base = blockIdx.x * 128;
    int t = threadIdx.x;
    int cg = t & 15, rg = t >> 4;
    int c0 = cg * 4, r0 = rg * 8;

    float acc[8][4];
    #pragma unroll
    for (int i = 0; i < 8; ++i)
        #pragma unroll
        for (int j = 0; j < 4; ++j) acc[i][j] = 0.f;

    int arow0 = t >> 3;
    int akq   = t & 7;

    for (int k0 = 0; k0 < 128; k0 += 32) {
        __syncthreads();
        #pragma unroll
        for (int i = 0; i < 4; ++i) {
            int row = arow0 + i * 32;
            int n = base + row;
            float4 v = make_float4(0.f, 0.f, 0.f, 0.f);
            if (n < N_NODES)
                v = *(const float4*)&x[(size_t)n * 128 + k0 + akq * 4];
            As[akq * 4 + 0][row] = v.x;
            As[akq * 4 + 1][row] = v.y;
            As[akq * 4 + 2][row] = v.z;
            As[akq * 4 + 3][row] = v.w;
        }
        #pragma unroll
        for (int i = 0; i < 2; ++i) {
            int idx = t + i * 256;
            int row = idx >> 4, q4 = idx & 15;
            *(float4*)&Ws[row][q4 * 4] =
                *(const float4*)&WX1[(size_t)(k0 + row) * 64 + q4 * 4];
        }
        __syncthreads();
        #pragma unroll 8
        for (int k = 0; k < 32; ++k) {
            float a[8];
            *(float4*)&a[0] = *(const float4*)&As[k][r0];
            *(float4*)&a[4] = *(const float4*)&As[k][r0 + 4];
            float4 w = *(const float4*)&Ws[k][c0];
            #pragma unroll
            for (int i = 0; i < 8; ++i) {
                acc[i][0] += a[i] * w.x;
                acc[i][1] += a[i] * w.y;
                acc[i][2] += a[i] * w.z;
                acc[i][3] += a[i] * w.w;
            }
        }
    }

    #pragma unroll
    for (int i = 0; i < 8; ++i) {
        int n = base + r0 + i;
        if (n < N_NODES)
            *(float4*)&px[(size_t)n * 64 + c0] = *(float4*)&acc[i][0];
    }
}

// ---------------- gather: pxs[n] = sum px[src], es[n] = sum ef[e] ----------------
// One wave per node. px: 1 float/lane (256B/row); ef: float2/lane (512B, NT).
// Masked 8-wide blocks: no serial tail; inactive slots clamp to edge m-1
// (duplicate load, L2-hit) and are masked out of the accumulate.
__global__ __launch_bounds__(256) void gather_kernel(
        const float* __restrict__ px, const float* __restrict__ ef,
        const int* __restrict__ cnt, const int* __restrict__ offs,
        const int2* __restrict__ epair,
        float* __restrict__ pxs, float* __restrict__ es) {
    int n    = (int)((blockIdx.x * 256 + threadIdx.x) >> 6);
    int lane = threadIdx.x & 63;
    if (n >= N_NODES) return;
    int off = offs[n], deg = cnt[n];
    int col2 = lane * 2;
    float apx = 0.f, ae0 = 0.f, ae1 = 0.f;
    for (int c0 = 0; c0 < deg; c0 += 64) {
        int j = c0 + lane;
        int2 p = make_int2(0, 0);
        if (j < deg) p = epair[off + j];
        int m = deg - c0; if (m > 64) m = 64;
        for (int j2 = 0; j2 < m; j2 += 8) {
            float xv[8]; v2f ev[8]; float msk[8];
            #pragma unroll
            for (int u = 0; u < 8; ++u) {
                int jj = j2 + u;
                int idx = (jj < m) ? jj : (m - 1);
                msk[u] = (jj < m) ? 1.f : 0.f;
                int e_ = __shfl(p.x, idx);
                int s_ = __shfl(p.y, idx);
                xv[u] = px[(size_t)s_ * 64 + lane];
                ev[u] = __builtin_nontemporal_load(
                            (const v2f*)(ef + (size_t)e_ * 128 + col2));
            }
            #pragma unroll
            for (int u = 0; u < 8; ++u) {
                apx += msk[u] * xv[u];
                ae0 += msk[u] * ev[u][0];
                ae1 += msk[u] * ev[u][1];
            }
        }
    }
    pxs[(size_t)n * 64 + lane] = apx;
    *(float2*)(es + (size_t)n * 128 + col2) = make_float2(ae0, ae1);
}

// ---------------- gemm1: u = x@WA[0:128] + es@WA[128:256] + pxs   [N,64] --------
__global__ __launch_bounds__(256) void gemm1_kernel(
        const float* __restrict__ x, const float* __restrict__ es,
        const float* __restrict__ pxs, const float* __restrict__ WA,
        float* __restrict__ u) {
    __shared__ float As[32][133];
    __shared__ float Ws[32][64];
    int base = blockIdx.x * 128;
    int t = threadIdx.x;
    int cg = t & 15, rg = t >> 4;
    int c0 = cg * 4, r0 = rg * 8;

    float acc[8][4];
    #pragma unroll
    for (int i = 0; i < 8; ++i) {
        int n = base + r0 + i;
        float4 pv = make_float4(0.f, 0.f, 0.f, 0.f);
        if (n < N_NODES) pv = *(const float4*)&pxs[(size_t)n * 64 + c0];
        acc[i][0] = pv.x; acc[i][1] = pv.y; acc[i][2] = pv.z; acc[i][3] = pv.w;
    }

    int arow0 = t >> 3;
    int akq   = t & 7;

    #pragma unroll
    for (int m = 0; m < 2; ++m) {
        const float* __restrict__ S = (m == 0) ? x : es;
        for (int k0 = 0; k0 < 128; k0 += 32) {
            __syncthreads();
            #pragma unroll
            for (int i = 0; i < 4; ++i) {
                int row = arow0 + i * 32;
                int n = base + row;
                float4 v = make_float4(0.f, 0.f, 0.f, 0.f);
                if (n < N_NODES)
                    v = *(const float4*)&S[(size_t)n * 128 + k0 + akq * 4];
                As[akq * 4 + 0][row] = v.x;
                As[akq * 4 + 1][row] = v.y;
                As[akq * 4 + 2][row] = v.z;
                As[akq * 4 + 3][row] = v.w;
            }
            #pragma unroll
            for (int i = 0; i < 2; ++i) {
                int idx = t + i * 256;
                int row = idx >> 4, q4 = idx & 15;
                *(float4*)&Ws[row][q4 * 4] =
                    *(const float4*)&WA[(size_t)(m * 128 + k0 + row) * 64 + q4 * 4];
            }
            __syncthreads();
            #pragma unroll 8
            for (int k = 0; k < 32; ++k) {
                float a[8];
                *(float4*)&a[0] = *(const float4*)&As[k][r0];
                *(float4*)&a[4] = *(const float4*)&As[k][r0 + 4];
                float4 w = *(const float4*)&Ws[k][c0];
                #pragma unroll
                for (int i = 0; i < 8; ++i) {
                    acc[i][0] += a[i] * w.x;
                    acc[i][1] += a[i] * w.y;
                    acc[i][2] += a[i] * w.z;
                    acc[i][3] += a[i] * w.w;
                }
            }
        }
    }

    #pragma unroll
    for (int i = 0; i < 8; ++i) {
        int n = base + r0 + i;
        if (n < N_NODES)
            *(float4*)&u[(size_t)n * 64 + c0] = *(float4*)&acc[i][0];
    }
}

// ---------------- gemm2: out = u @ W_em + deg*r + c2   [N,128], K=64 ----------
__global__ __launch_bounds__(256) void gemm2_kernel(
        const float* __restrict__ u, const int* __restrict__ cnt,
        const float* __restrict__ W_em,
        const float* __restrict__ rvec, const float* __restrict__ c2,
        float* __restrict__ out) {
    __shared__ float UsT[64][69];
    __shared__ float Wem[64][128];
    int base = blockIdx.x * 64;
    int t = threadIdx.x;
    int cg = t & 15, rg = t >> 4;
    int c0 = cg * 8, r0 = rg * 4;

    #pragma unroll
    for (int i = 0; i < 4; ++i) {
        int idx = t + i * 256;
        int row = idx >> 4, kq = idx & 15;
        int n = base + row;
        float4 v = make_float4(0.f, 0.f, 0.f, 0.f);
        if (n < N_NODES) v = *(const float4*)&u[(size_t)n * 64 + kq * 4];
        UsT[kq * 4 + 0][row] = v.x;
        UsT[kq * 4 + 1][row] = v.y;
        UsT[kq * 4 + 2][row] = v.z;
        UsT[kq * 4 + 3][row] = v.w;
    }
    #pragma unroll
    for (int i = 0; i < 8; ++i) {
        int idx = t + i * 256;
        int row = idx >> 5, q4 = idx & 31;
        *(float4*)&Wem[row][q4 * 4] = *(const float4*)&W_em[(size_t)row * 128 + q4 * 4];
    }

    float4 rva = *(const float4*)&rvec[c0];
    float4 rvb = *(const float4*)&rvec[c0 + 4];
    float4 cva = *(const float4*)&c2[c0];
    float4 cvb = *(const float4*)&c2[c0 + 4];
    float acc[4][8];
    #pragma unroll
    for (int i = 0; i < 4; ++i) {
        int n = base + r0 + i;
        float dg = (n < N_NODES) ? (float)cnt[n] : 0.f;
        acc[i][0] = cva.x + dg * rva.x;  acc[i][1] = cva.y + dg * rva.y;
        acc[i][2] = cva.z + dg * rva.z;  acc[i][3] = cva.w + dg * rva.w;
        acc[i][4] = cvb.x + dg * rvb.x;  acc[i][5] = cvb.y + dg * rvb.y;
        acc[i][6] = cvb.z + dg * rvb.z;  acc[i][7] = cvb.w + dg * rvb.w;
    }
    __syncthreads();

    #pragma unroll 8
    for (int k = 0; k < 64; ++k) {
        float a[4], w[8];
        *(float4*)&a[0] = *(const float4*)&UsT[k][r0];
        *(float4*)&w[0] = *(const float4*)&Wem[k][c0];
        *(float4*)&w[4] = *(const float4*)&Wem[k][c0 + 4];
        #pragma unroll
        for (int i = 0; i < 4; ++i)
            #pragma unroll
            for (int j = 0; j < 8; ++j)
                acc[i][j] += a[i] * w[j];
    }

    #pragma unroll
    for (int i = 0; i < 4; ++i) {
        int n = base + r0 + i;
        if (n < N_NODES) {
            *(float4*)&out[(size_t)n * 128 + c0]     = *(float4*)&acc[i][0];
            *(float4*)&out[(size_t)n * 128 + c0 + 4] = *(float4*)&acc[i][4];
        }
    }
}

extern "C" void kernel_launch(void* const* d_in, const int* in_sizes, int n_in,
                              void* d_out, int out_size, void* d_ws, size_t ws_size,
                              hipStream_t stream) {
    const float* x     = (const float*)d_in[0];
    const float* ef    = (const float*)d_in[1];
    const int*   src   = (const int*)d_in[2];
    const int*   dst   = (const int*)d_in[3];
    const float* W_nl1 = (const float*)d_in[4];
    const float* b_nl1 = (const float*)d_in[5];
    const float* W_el  = (const float*)d_in[6];
    const float* b_el  = (const float*)d_in[7];
    const float* W1    = (const float*)d_in[8];
    const float* b1    = (const float*)d_in[9];
    const float* W2    = (const float*)d_in[10];
    const float* b2    = (const float*)d_in[11];
    const float* W_nl2 = (const float*)d_in[12];
    const float* b_nl2 = (const float*)d_in[13];
    const float* W_ml  = (const float*)d_in[14];
    const float* b_ml  = (const float*)d_in[15];
    const float* W_em  = (const float*)d_in[16];
    const float* b_em  = (const float*)d_in[17];

    int*   wsI = (int*)d_ws;
    float* wsF = (float*)d_ws;
    float* px     = wsF + WF_PX;
    float* es     = wsF + WF_ES;
    float* pxs    = wsF + WF_PXS;
    float* uN     = wsF + WF_UN;
    int*   cnt    = wsI + WI_CNT;
    int*   offs   = wsI + WI_OFF;
    int*   cursor = wsI + WI_CUR;
    int*   bsum   = wsI + WI_BSUM;
    int*   boff   = wsI + WI_BOFF;
    int2*  epair  = (int2*)(wsI + WI_EPAIR);
    float* T2   = wsF + WF_T2;
    float* be_g = wsF + WF_BEG;
    float* rh_g = wsF + WF_RH;
    float* K1   = wsF + WF_K1;
    float* WA   = wsF + WF_WA;
    float* WX1  = wsF + WF_WX1;
    float* r    = wsF + WF_R;
    float* c2   = wsF + WF_C2;

    // precompute chain (tiny)
    pre_t2_kernel<<<17, 256, 0, stream>>>(W2, W_ml, b1, b2, T2, be_g);
    pre_k1_kernel<<<16, 256, 0, stream>>>(W1, T2, K1);
    pre_wa_kernel<<<97, 256, 0, stream>>>(W_nl1, W_el, W_nl2, K1,
                                          b_nl1, b_el, be_g, W_ml, WA, WX1, rh_g);
    pre_rc_kernel<<<1, 256, 0, stream>>>(rh_g, W_em, b_nl2, b_ml, b_em, r, c2);

    // CSR build
    zero_kernel<<<NBLK_SCAN, 256, 0, stream>>>(cnt);
    hist_kernel<<<(N_EDGES + 255) / 256, 256, 0, stream>>>(dst, cnt);
    scan_a_kernel<<<NBLK_SCAN, 256, 0, stream>>>(cnt, bsum);
    scan_b_kernel<<<1, 256, 0, stream>>>(bsum, boff);
    scan_c_kernel<<<NBLK_SCAN, 256, 0, stream>>>(cnt, boff, offs, cursor);
    fill_kernel<<<(N_EDGES + 255) / 256, 256, 0, stream>>>(dst, src, cursor, epair);

    // x projection (before gather)
    px_kernel<<<(N_NODES + 127) / 128, 256, 0, stream>>>(x, WX1, px);

    // gather: one wave per node
    gather_kernel<<<(N_NODES + 3) / 4, 256, 0, stream>>>(
        px, ef, cnt, offs, epair, pxs, es);

    gemm1_kernel<<<(N_NODES + 127) / 128, 256, 0, stream>>>(x, es, pxs, WA, uN);
    gemm2_kernel<<<(N_NODES + 63) / 64, 256, 0, stream>>>(
        uN, cnt, W_em, r, c2, (float*)d_out);
}